// Round 1
// baseline (1602.828 us; speedup 1.0000x reference)
//
#include <hip/hip_runtime.h>
#include <math.h>

#define LQ 1024      // sequence length
#define EE 1024      // embed dim
#define NH 16        // heads
#define HD 64        // head dim
#define NBH 64       // B*H
#define SCALING 0.125f

// ---------------------------------------------------------------------------
// QKV projection: C = hidden(4096x1024) @ W(1024x1024) + b  (q also *SCALING)
// scattered to (b*H+h, t, d) layout for the attention kernel.
// Tile: BM=BN=64, BK=16, 256 threads, 4x4 per thread. fp32.
// ---------------------------------------------------------------------------
__global__ __launch_bounds__(256) void qkv_gemm(
    const float* __restrict__ A,
    const float* __restrict__ Wq, const float* __restrict__ Wk, const float* __restrict__ Wv,
    const float* __restrict__ bq, const float* __restrict__ bk, const float* __restrict__ bv,
    float* __restrict__ qo, float* __restrict__ ko, float* __restrict__ vo)
{
    const int z = blockIdx.z;
    const float* __restrict__ W    = (z == 0) ? Wq : (z == 1 ? Wk : Wv);
    const float* __restrict__ bias = (z == 0) ? bq : (z == 1 ? bk : bv);
    float* __restrict__ O          = (z == 0) ? qo : (z == 1 ? ko : vo);

    const int n0 = blockIdx.x * 64;
    const int m0 = blockIdx.y * 64;
    const int tid = threadIdx.x;
    const int ty = tid >> 4, tx = tid & 15;

    __shared__ float As[16 * 68];   // [k][m], padded
    __shared__ float Bs[16 * 68];   // [k][n], padded

    float acc[4][4] = {};

    for (int k0 = 0; k0 < EE; k0 += 16) {
        // A tile: 64 rows x 16 k, one float4 per thread
        {
            int mm = tid >> 2, kq = tid & 3;
            float4 a = *(const float4*)&A[(size_t)(m0 + mm) * EE + k0 + kq * 4];
            As[(kq * 4 + 0) * 68 + mm] = a.x;
            As[(kq * 4 + 1) * 68 + mm] = a.y;
            As[(kq * 4 + 2) * 68 + mm] = a.z;
            As[(kq * 4 + 3) * 68 + mm] = a.w;
        }
        // B tile: 16 k x 64 n
        {
            int kk = tid >> 4, nq = tid & 15;
            float4 b = *(const float4*)&W[(size_t)(k0 + kk) * EE + n0 + nq * 4];
            *(float4*)&Bs[kk * 68 + nq * 4] = b;
        }
        __syncthreads();
#pragma unroll
        for (int kk = 0; kk < 16; kk++) {
            float4 av = *(float4*)&As[kk * 68 + ty * 4];
            float4 bv4 = *(float4*)&Bs[kk * 68 + tx * 4];
            float a_[4] = {av.x, av.y, av.z, av.w};
            float b_[4] = {bv4.x, bv4.y, bv4.z, bv4.w};
#pragma unroll
            for (int i = 0; i < 4; i++)
#pragma unroll
                for (int j = 0; j < 4; j++)
                    acc[i][j] += a_[i] * b_[j];
        }
        __syncthreads();
    }

#pragma unroll
    for (int i = 0; i < 4; i++) {
        int m = m0 + ty * 4 + i;
        int b = m >> 10, t = m & 1023;
#pragma unroll
        for (int j = 0; j < 4; j++) {
            int n = n0 + tx * 4 + j;
            float v = acc[i][j] + bias[n];
            if (z == 0) v *= SCALING;
            int h = n >> 6, d = n & 63;
            O[(size_t)((b * NH + h) * LQ + t) * HD + d] = v;
        }
    }
}

// ---------------------------------------------------------------------------
// Output projection: out = attn(4096x1024) @ Wo + bo, row-major output.
// ---------------------------------------------------------------------------
__global__ __launch_bounds__(256) void out_gemm(
    const float* __restrict__ A, const float* __restrict__ W,
    const float* __restrict__ bias, float* __restrict__ O)
{
    const int n0 = blockIdx.x * 64;
    const int m0 = blockIdx.y * 64;
    const int tid = threadIdx.x;
    const int ty = tid >> 4, tx = tid & 15;

    __shared__ float As[16 * 68];
    __shared__ float Bs[16 * 68];

    float acc[4][4] = {};

    for (int k0 = 0; k0 < EE; k0 += 16) {
        {
            int mm = tid >> 2, kq = tid & 3;
            float4 a = *(const float4*)&A[(size_t)(m0 + mm) * EE + k0 + kq * 4];
            As[(kq * 4 + 0) * 68 + mm] = a.x;
            As[(kq * 4 + 1) * 68 + mm] = a.y;
            As[(kq * 4 + 2) * 68 + mm] = a.z;
            As[(kq * 4 + 3) * 68 + mm] = a.w;
        }
        {
            int kk = tid >> 4, nq = tid & 15;
            float4 b = *(const float4*)&W[(size_t)(k0 + kk) * EE + n0 + nq * 4];
            *(float4*)&Bs[kk * 68 + nq * 4] = b;
        }
        __syncthreads();
#pragma unroll
        for (int kk = 0; kk < 16; kk++) {
            float4 av = *(float4*)&As[kk * 68 + ty * 4];
            float4 bv4 = *(float4*)&Bs[kk * 68 + tx * 4];
            float a_[4] = {av.x, av.y, av.z, av.w};
            float b_[4] = {bv4.x, bv4.y, bv4.z, bv4.w};
#pragma unroll
            for (int i = 0; i < 4; i++)
#pragma unroll
                for (int j = 0; j < 4; j++)
                    acc[i][j] += a_[i] * b_[j];
        }
        __syncthreads();
    }

#pragma unroll
    for (int i = 0; i < 4; i++) {
        int m = m0 + ty * 4 + i;
#pragma unroll
        for (int j = 0; j < 4; j++) {
            int n = n0 + tx * 4 + j;
            O[(size_t)m * EE + n] = acc[i][j] + bias[n];
        }
    }
}

// ---------------------------------------------------------------------------
// Attention with windowed relative-position terms.
// One block = one (bh) x 8 query rows. Exact two-pass softmax, scores in LDS.
//   S[t][s] = q[t].k[s] + (|s-t|<=4 ? q[t].relk[s-t+4] : 0)
//   O[t]    = sum_s P[t][s] v[s] + sum_{r=-4..4} P[t][t+r] relv[r+4]
// Writes attn output directly in (B, L, E) layout (e = h*64+d).
// ---------------------------------------------------------------------------
__global__ __launch_bounds__(256) void attn_kernel(
    const float* __restrict__ qw, const float* __restrict__ kw, const float* __restrict__ vw,
    const float* __restrict__ relk, const float* __restrict__ relv,
    float* __restrict__ aout)
{
    const int bh = blockIdx.y;
    const int t0 = blockIdx.x * 8;
    const int tid = threadIdx.x;

    __shared__ float sc[8 * 1024];   // scores -> probs (unnormalized)
    __shared__ float kv[64 * 67];    // K/V chunk, padded stride 67
    __shared__ float qs[8 * 67];     // Q rows
    __shared__ float rsum[8];        // 1/sum per row

    // load 8 q rows
    if (tid < 128) {
        int tl = tid >> 4, dq = tid & 15;
        float4 a = *(const float4*)&qw[(size_t)(bh * LQ + t0 + tl) * HD + dq * 4];
        qs[tl * 67 + dq * 4 + 0] = a.x;
        qs[tl * 67 + dq * 4 + 1] = a.y;
        qs[tl * 67 + dq * 4 + 2] = a.z;
        qs[tl * 67 + dq * 4 + 3] = a.w;
    }
    __syncthreads();

    // ---- phase 1: scores = q @ k^T, chunked over s ----
    for (int s0 = 0; s0 < LQ; s0 += 64) {
        const float* kg = kw + (size_t)(bh * LQ + s0) * HD;
#pragma unroll
        for (int r = 0; r < 4; r++) {
            int f = r * 256 + tid;          // float4 index 0..1023
            int sl = f >> 4, dq = f & 15;
            float4 a = *(const float4*)&kg[sl * HD + dq * 4];
            kv[sl * 67 + dq * 4 + 0] = a.x;
            kv[sl * 67 + dq * 4 + 1] = a.y;
            kv[sl * 67 + dq * 4 + 2] = a.z;
            kv[sl * 67 + dq * 4 + 3] = a.w;
        }
        __syncthreads();
#pragma unroll
        for (int e = 0; e < 2; e++) {
            int idx = e * 256 + tid;
            int tl = idx >> 6, sl = idx & 63;
            float acc = 0.f;
#pragma unroll
            for (int d = 0; d < 64; d++) acc += qs[tl * 67 + d] * kv[sl * 67 + d];
            sc[tl * 1024 + s0 + sl] = acc;
        }
        __syncthreads();
    }

    // ---- rel-k window bias ----
    if (tid < 72) {
        int tl = tid / 9, i = tid % 9;
        int s = t0 + tl + i - 4;
        if (s >= 0 && s < LQ) {
            float acc = 0.f;
#pragma unroll
            for (int d = 0; d < 64; d++) acc += qs[tl * 67 + d] * relk[i * 64 + d];
            sc[tl * 1024 + s] += acc;
        }
    }
    __syncthreads();

    // ---- phase 2: softmax per row (32 threads / row) ----
    {
        int tl = tid >> 5, j = tid & 31;
        float mx = -1e30f;
#pragma unroll
        for (int mm = 0; mm < 32; mm++) mx = fmaxf(mx, sc[tl * 1024 + mm * 32 + j]);
#pragma unroll
        for (int mask = 16; mask >= 1; mask >>= 1) mx = fmaxf(mx, __shfl_xor(mx, mask, 32));
        float sum = 0.f;
#pragma unroll
        for (int mm = 0; mm < 32; mm++) {
            int ix = tl * 1024 + mm * 32 + j;
            float p = __expf(sc[ix] - mx);
            sc[ix] = p;
            sum += p;
        }
#pragma unroll
        for (int mask = 16; mask >= 1; mask >>= 1) sum += __shfl_xor(sum, mask, 32);
        if (j == 0) rsum[tl] = 1.0f / sum;
    }
    __syncthreads();

    // ---- phase 3: O = P @ V ----
    const int tlA = tid >> 6;     // rows 0..3
    const int tlB = tlA + 4;      // rows 4..7
    const int d = tid & 63;
    float acc0 = 0.f, acc1 = 0.f;

    for (int s0 = 0; s0 < LQ; s0 += 64) {
        const float* vg = vw + (size_t)(bh * LQ + s0) * HD;
#pragma unroll
        for (int r = 0; r < 4; r++) {
            int f = r * 256 + tid;
            int sl = f >> 4, dq = f & 15;
            float4 a = *(const float4*)&vg[sl * HD + dq * 4];
            kv[sl * 67 + dq * 4 + 0] = a.x;
            kv[sl * 67 + dq * 4 + 1] = a.y;
            kv[sl * 67 + dq * 4 + 2] = a.z;
            kv[sl * 67 + dq * 4 + 3] = a.w;
        }
        __syncthreads();
#pragma unroll
        for (int sl = 0; sl < 64; sl++) {
            float vv = kv[sl * 67 + d];
            acc0 += sc[tlA * 1024 + s0 + sl] * vv;
            acc1 += sc[tlB * 1024 + s0 + sl] * vv;
        }
        __syncthreads();
    }

    // ---- rel-v window term + normalize + write ----
    const int b = bh >> 4, h = bh & 15;
    {
        int t = t0 + tlA;
        float val = acc0;
#pragma unroll
        for (int i = 0; i < 9; i++) {
            int s = t + i - 4;
            if (s >= 0 && s < LQ) val += sc[tlA * 1024 + s] * relv[i * 64 + d];
        }
        aout[(size_t)(b * LQ + t) * EE + h * HD + d] = val * rsum[tlA];
    }
    {
        int t = t0 + tlB;
        float val = acc1;
#pragma unroll
        for (int i = 0; i < 9; i++) {
            int s = t + i - 4;
            if (s >= 0 && s < LQ) val += sc[tlB * 1024 + s] * relv[i * 64 + d];
        }
        aout[(size_t)(b * LQ + t) * EE + h * HD + d] = val * rsum[tlB];
    }
}

// ---------------------------------------------------------------------------
extern "C" void kernel_launch(void* const* d_in, const int* in_sizes, int n_in,
                              void* d_out, int out_size, void* d_ws, size_t ws_size,
                              hipStream_t stream)
{
    const float* hidden = (const float*)d_in[0];
    const float* Wq = (const float*)d_in[1];
    const float* bq = (const float*)d_in[2];
    const float* Wk = (const float*)d_in[3];
    const float* bk = (const float*)d_in[4];
    const float* Wv = (const float*)d_in[5];
    const float* bv = (const float*)d_in[6];
    const float* Wo = (const float*)d_in[7];
    const float* bo = (const float*)d_in[8];
    const float* relk = (const float*)d_in[9];
    const float* relv = (const float*)d_in[10];

    float* ws = (float*)d_ws;
    float* qw  = ws;                       // (64,1024,64) fp32 = 16 MB
    float* kw  = ws + (1u << 22);          // 16 MB
    float* vw  = ws + (2u << 22);          // 16 MB
    float* aow = ws + 3u * (1u << 22);     // (4,1024,1024) fp32 = 16 MB
    float* out = (float*)d_out;

    // 1) QKV projections (+bias, +q scaling, scatter to per-head layout)
    qkv_gemm<<<dim3(16, 64, 3), 256, 0, stream>>>(hidden, Wq, Wk, Wv, bq, bk, bv, qw, kw, vw);
    // 2) attention with windowed relative-position terms
    attn_kernel<<<dim3(128, 64), 256, 0, stream>>>(qw, kw, vw, relk, relv, aow);
    // 3) output projection
    out_gemm<<<dim3(16, 64), 256, 0, stream>>>(aow, Wo, bo, out);
}

// Round 2
// 533.684 us; speedup vs baseline: 3.0033x; 3.0033x over previous
//
#include <hip/hip_runtime.h>
#include <math.h>

#define LQ 1024      // sequence length
#define EE 1024      // embed dim
#define NH 16        // heads
#define HD 64        // head dim
#define NBH 64       // B*H
#define SCALING 0.125f

typedef unsigned short u16;
typedef __bf16 bf16x8 __attribute__((ext_vector_type(8)));
typedef float f32x4 __attribute__((ext_vector_type(4)));

#define MFMA16(a, b, c) __builtin_amdgcn_mfma_f32_16x16x32_bf16(a, b, c, 0, 0, 0)

// ---------------------------------------------------------------------------
// QKV projection: C = hidden(4096x1024) @ W(1024x1024) + b  (q also *SCALING)
// writes bf16 outputs scattered to (b*H+h, t, d) layout.
// ---------------------------------------------------------------------------
__global__ __launch_bounds__(256) void qkv_gemm(
    const float* __restrict__ A,
    const float* __restrict__ Wq, const float* __restrict__ Wk, const float* __restrict__ Wv,
    const float* __restrict__ bq, const float* __restrict__ bk, const float* __restrict__ bv,
    __bf16* __restrict__ qo, __bf16* __restrict__ ko, __bf16* __restrict__ vo)
{
    const int z = blockIdx.z;
    const float* __restrict__ W    = (z == 0) ? Wq : (z == 1 ? Wk : Wv);
    const float* __restrict__ bias = (z == 0) ? bq : (z == 1 ? bk : bv);
    __bf16* __restrict__ O         = (z == 0) ? qo : (z == 1 ? ko : vo);

    const int n0 = blockIdx.x * 64;
    const int m0 = blockIdx.y * 64;
    const int tid = threadIdx.x;
    const int ty = tid >> 4, tx = tid & 15;

    __shared__ float As[16 * 68];   // [k][m], padded
    __shared__ float Bs[16 * 68];   // [k][n], padded

    float acc[4][4] = {};

    for (int k0 = 0; k0 < EE; k0 += 16) {
        {
            int mm = tid >> 2, kq = tid & 3;
            float4 a = *(const float4*)&A[(size_t)(m0 + mm) * EE + k0 + kq * 4];
            As[(kq * 4 + 0) * 68 + mm] = a.x;
            As[(kq * 4 + 1) * 68 + mm] = a.y;
            As[(kq * 4 + 2) * 68 + mm] = a.z;
            As[(kq * 4 + 3) * 68 + mm] = a.w;
        }
        {
            int kk = tid >> 4, nq = tid & 15;
            float4 b = *(const float4*)&W[(size_t)(k0 + kk) * EE + n0 + nq * 4];
            *(float4*)&Bs[kk * 68 + nq * 4] = b;
        }
        __syncthreads();
#pragma unroll
        for (int kk = 0; kk < 16; kk++) {
            float4 av = *(float4*)&As[kk * 68 + ty * 4];
            float4 bv4 = *(float4*)&Bs[kk * 68 + tx * 4];
            float a_[4] = {av.x, av.y, av.z, av.w};
            float b_[4] = {bv4.x, bv4.y, bv4.z, bv4.w};
#pragma unroll
            for (int i = 0; i < 4; i++)
#pragma unroll
                for (int j = 0; j < 4; j++)
                    acc[i][j] += a_[i] * b_[j];
        }
        __syncthreads();
    }

#pragma unroll
    for (int i = 0; i < 4; i++) {
        int m = m0 + ty * 4 + i;
        int b = m >> 10, t = m & 1023;
#pragma unroll
        for (int j = 0; j < 4; j++) {
            int n = n0 + tx * 4 + j;
            float v = acc[i][j] + bias[n];
            if (z == 0) v *= SCALING;
            int h = n >> 6, d = n & 63;
            O[(size_t)((b * NH + h) * LQ + t) * HD + d] = (__bf16)v;
        }
    }
}

// ---------------------------------------------------------------------------
// Output projection: out = attn(4096x1024) @ Wo + bo, fp32.
// ---------------------------------------------------------------------------
__global__ __launch_bounds__(256) void out_gemm(
    const float* __restrict__ A, const float* __restrict__ W,
    const float* __restrict__ bias, float* __restrict__ O)
{
    const int n0 = blockIdx.x * 64;
    const int m0 = blockIdx.y * 64;
    const int tid = threadIdx.x;
    const int ty = tid >> 4, tx = tid & 15;

    __shared__ float As[16 * 68];
    __shared__ float Bs[16 * 68];

    float acc[4][4] = {};

    for (int k0 = 0; k0 < EE; k0 += 16) {
        {
            int mm = tid >> 2, kq = tid & 3;
            float4 a = *(const float4*)&A[(size_t)(m0 + mm) * EE + k0 + kq * 4];
            As[(kq * 4 + 0) * 68 + mm] = a.x;
            As[(kq * 4 + 1) * 68 + mm] = a.y;
            As[(kq * 4 + 2) * 68 + mm] = a.z;
            As[(kq * 4 + 3) * 68 + mm] = a.w;
        }
        {
            int kk = tid >> 4, nq = tid & 15;
            float4 b = *(const float4*)&W[(size_t)(k0 + kk) * EE + n0 + nq * 4];
            *(float4*)&Bs[kk * 68 + nq * 4] = b;
        }
        __syncthreads();
#pragma unroll
        for (int kk = 0; kk < 16; kk++) {
            float4 av = *(float4*)&As[kk * 68 + ty * 4];
            float4 bv4 = *(float4*)&Bs[kk * 68 + tx * 4];
            float a_[4] = {av.x, av.y, av.z, av.w};
            float b_[4] = {bv4.x, bv4.y, bv4.z, bv4.w};
#pragma unroll
            for (int i = 0; i < 4; i++)
#pragma unroll
                for (int j = 0; j < 4; j++)
                    acc[i][j] += a_[i] * b_[j];
        }
        __syncthreads();
    }

#pragma unroll
    for (int i = 0; i < 4; i++) {
        int m = m0 + ty * 4 + i;
#pragma unroll
        for (int j = 0; j < 4; j++) {
            int n = n0 + tx * 4 + j;
            O[(size_t)m * EE + n] = acc[i][j] + bias[n];
        }
    }
}

// ---------------------------------------------------------------------------
// V transpose: vb[bh][s][d] bf16 -> vtb[bh][d][s] bf16 (per 64-s tile)
// ---------------------------------------------------------------------------
__global__ __launch_bounds__(256) void vtrans(
    const __bf16* __restrict__ vb, __bf16* __restrict__ vtb)
{
    const int bh = blockIdx.y;
    const int s0 = blockIdx.x * 64;
    const int tid = threadIdx.x;
    __shared__ float t[64][65];

#pragma unroll
    for (int rr = 0; rr < 2; rr++) {
        int f = rr * 256 + tid;
        int s = f >> 3, c8 = f & 7;
        bf16x8 v = *(const bf16x8*)(vb + ((size_t)bh * LQ + s0 + s) * HD + c8 * 8);
#pragma unroll
        for (int j = 0; j < 8; j++) t[c8 * 8 + j][s] = (float)v[j];
    }
    __syncthreads();
#pragma unroll
    for (int rr = 0; rr < 2; rr++) {
        int f = rr * 256 + tid;
        int d = f >> 3, c8 = f & 7;
        bf16x8 o;
#pragma unroll
        for (int j = 0; j < 8; j++) o[j] = (__bf16)t[d][c8 * 8 + j];
        *(bf16x8*)(vtb + ((size_t)bh * HD + d) * LQ + s0 + c8 * 8) = o;
    }
}

// ---------------------------------------------------------------------------
// MFMA flash attention with windowed relative-position terms.
// Block: one bh x 64 q-rows. 4 waves, wave owns 16 q-rows. KV chunk = 64.
// LDS tiles are 64x64 bf16, XOR-swizzled: byte ^= (row&7)<<4 (16B slots).
// Staged via global_load_lds (linear dest) with inverse-swizzled source.
// ---------------------------------------------------------------------------
__device__ __forceinline__ bf16x8 ld_frag(const u16* base, int row, int col)
{
    int off = (row * 128 + col * 2) ^ ((row & 7) << 4);
    return *(const bf16x8*)((const char*)base + off);
}

__global__ __launch_bounds__(256) void attn_mfma(
    const u16* __restrict__ qb, const u16* __restrict__ kb,
    const u16* __restrict__ vtb,
    const float* __restrict__ relk, const float* __restrict__ relv,
    float* __restrict__ aout)
{
    __shared__ __attribute__((aligned(16))) u16 q_lds[64 * 64];
    __shared__ __attribute__((aligned(16))) u16 k_lds[64 * 64];
    __shared__ __attribute__((aligned(16))) u16 v_lds[64 * 64];
    __shared__ __attribute__((aligned(16))) u16 p_lds[64 * 64];  // wave-private 16x64 regions
    __shared__ float R_lds[64 * 9];
    __shared__ float rk_lds[9 * 64];
    __shared__ float rv_lds[9 * 64];

    const int tid  = threadIdx.x;
    const int lane = tid & 63;
    const int wave = tid >> 6;
    const int bh   = blockIdx.y;
    const int q0   = blockIdx.x * 64;

    // ---- stage Q block (64x64 bf16) with inverse-swizzled source ----
#pragma unroll
    for (int rr = 0; rr < 2; rr++) {
        int f = rr * 256 + tid;
        int row = f >> 3, c8 = f & 7;
        const u16* src = qb + ((size_t)bh * LQ + q0 + row) * HD + ((c8 ^ (row & 7)) * 8);
        __builtin_amdgcn_global_load_lds(src, q_lds + (size_t)(f & ~63) * 8, 16, 0, 0);
    }
    // ---- stage relk / relv (9x64 fp32 each) ----
    for (int u = tid; u < 144; u += 256)
        *(float4*)&rk_lds[u * 4] = *(const float4*)&relk[u * 4];
    for (int u = tid; u < 144; u += 256)
        *(float4*)&rv_lds[u * 4] = *(const float4*)&relv[u * 4];
    __syncthreads();

    // ---- R[t][i] = q[t] . relk[i]  (64 x 9) ----
    for (int j = tid; j < 576; j += 256) {
        int tl = j / 9, i = j - tl * 9;
        float acc = 0.f;
        for (int d = 0; d < 64; d++) {
            int off = (tl * 128 + d * 2) ^ ((tl & 7) << 4);
            float qv = (float)*(const __bf16*)((const char*)q_lds + off);
            acc += qv * rk_lds[i * 64 + d];
        }
        R_lds[tl * 9 + i] = acc;
    }

    // ---- per-wave Q A-frags (loop-invariant) ----
    bf16x8 qa[2];
    qa[0] = ld_frag(q_lds, wave * 16 + (lane & 15), (lane >> 4) * 8);
    qa[1] = ld_frag(q_lds, wave * 16 + (lane & 15), 32 + (lane >> 4) * 8);

    __syncthreads();  // R_lds ready for all waves

    f32x4 of[4] = {};         // O accum: d-subtile x (4 q-rows per lane)
    float m_r[4], l_r[4];
#pragma unroll
    for (int r = 0; r < 4; r++) { m_r[r] = -1e30f; l_r[r] = 0.f; }

    const u16* pw = p_lds + wave * 1024;   // 16x64 wave-private P tile
    u16* pww      = p_lds + wave * 1024;

    for (int s0 = 0; s0 < LQ; s0 += 64) {
        // ---- stage K chunk [s][d] and Vt chunk [d][s] ----
#pragma unroll
        for (int rr = 0; rr < 2; rr++) {
            int f = rr * 256 + tid;
            int row = f >> 3, c8 = f & 7;
            const u16* srck = kb + ((size_t)bh * LQ + s0 + row) * HD + ((c8 ^ (row & 7)) * 8);
            __builtin_amdgcn_global_load_lds(srck, k_lds + (size_t)(f & ~63) * 8, 16, 0, 0);
            const u16* srcv = vtb + ((size_t)bh * HD + row) * LQ + s0 + ((c8 ^ (row & 7)) * 8);
            __builtin_amdgcn_global_load_lds(srcv, v_lds + (size_t)(f & ~63) * 8, 16, 0, 0);
        }
        __syncthreads();

        // ---- S = Q @ K^T  (16 q x 64 s per wave) ----
        f32x4 sf[4] = {};
#pragma unroll
        for (int sub = 0; sub < 4; sub++) {
#pragma unroll
            for (int kk = 0; kk < 2; kk++) {
                bf16x8 kf = ld_frag(k_lds, sub * 16 + (lane & 15), kk * 32 + (lane >> 4) * 8);
                sf[sub] = MFMA16(qa[kk], kf, sf[sub]);
            }
        }

        // ---- windowed rel-k bias (diag-adjacent chunks only) ----
        int drel = s0 - q0;
        bool diag = (drel == -64) || (drel == 0) || (drel == 64);
        if (diag) {
#pragma unroll
            for (int sub = 0; sub < 4; sub++) {
#pragma unroll
                for (int r = 0; r < 4; r++) {
                    int tl = wave * 16 + (lane >> 4) * 4 + r;
                    int s  = s0 + sub * 16 + (lane & 15);
                    int i  = s - (q0 + tl) + 4;
                    if ((unsigned)i <= 8u) sf[sub][r] += R_lds[tl * 9 + i];
                }
            }
        }

        // ---- online softmax update ----
        float tmax[4];
#pragma unroll
        for (int r = 0; r < 4; r++) {
            float m0 = fmaxf(fmaxf(sf[0][r], sf[1][r]), fmaxf(sf[2][r], sf[3][r]));
#pragma unroll
            for (int msk = 8; msk >= 1; msk >>= 1) m0 = fmaxf(m0, __shfl_xor(m0, msk, 64));
            tmax[r] = m0;
        }
#pragma unroll
        for (int r = 0; r < 4; r++) {
            float mn = fmaxf(m_r[r], tmax[r]);
            float sc = __expf(m_r[r] - mn);
            m_r[r] = mn;
            l_r[r] *= sc;
#pragma unroll
            for (int sub = 0; sub < 4; sub++) of[sub][r] *= sc;
        }
        // P = exp(S - m), accumulate row-sum partials, write bf16 to p_lds
#pragma unroll
        for (int sub = 0; sub < 4; sub++) {
#pragma unroll
            for (int r = 0; r < 4; r++) {
                float p = __expf(sf[sub][r] - m_r[r]);
                l_r[r] += p;
                int q = (lane >> 4) * 4 + r;
                int off = (q * 128 + (sub * 16 + (lane & 15)) * 2) ^ ((q & 7) << 4);
                *(__bf16*)((char*)pww + off) = (__bf16)p;
            }
        }

        // ---- O += P @ V ----
#pragma unroll
        for (int kk = 0; kk < 2; kk++) {
            bf16x8 pa = ld_frag(pw, lane & 15, kk * 32 + (lane >> 4) * 8);
#pragma unroll
            for (int dsub = 0; dsub < 4; dsub++) {
                bf16x8 vf = ld_frag(v_lds, dsub * 16 + (lane & 15), kk * 32 + (lane >> 4) * 8);
                of[dsub] = MFMA16(pa, vf, of[dsub]);
            }
        }

        // ---- windowed rel-v term (diag-adjacent chunks only) ----
        if (diag) {
#pragma unroll
            for (int r = 0; r < 4; r++) {
                int q  = (lane >> 4) * 4 + r;
                int tl = wave * 16 + q;
#pragma unroll
                for (int i = 0; i < 9; i++) {
                    int s  = q0 + tl + i - 4;
                    int sl = s - s0;
                    if ((unsigned)sl < 64u) {
                        int off = (q * 128 + sl * 2) ^ ((q & 7) << 4);
                        float p = (float)*(const __bf16*)((const char*)pww + off);
#pragma unroll
                        for (int dsub = 0; dsub < 4; dsub++)
                            of[dsub][r] += p * rv_lds[i * 64 + dsub * 16 + (lane & 15)];
                    }
                }
            }
        }
        __syncthreads();   // protect k/v_lds before next staging
    }

    // ---- final normalize + write (B, L, E) fp32 ----
#pragma unroll
    for (int r = 0; r < 4; r++) {
        float s = l_r[r];
#pragma unroll
        for (int msk = 8; msk >= 1; msk >>= 1) s += __shfl_xor(s, msk, 64);
        l_r[r] = 1.0f / s;
    }
    const int b = bh >> 4, h = bh & 15;
#pragma unroll
    for (int dsub = 0; dsub < 4; dsub++) {
#pragma unroll
        for (int r = 0; r < 4; r++) {
            int t = q0 + wave * 16 + (lane >> 4) * 4 + r;
            int e = h * 64 + dsub * 16 + (lane & 15);
            aout[((size_t)b * LQ + t) * EE + e] = of[dsub][r] * l_r[r];
        }
    }
}

// ---------------------------------------------------------------------------
extern "C" void kernel_launch(void* const* d_in, const int* in_sizes, int n_in,
                              void* d_out, int out_size, void* d_ws, size_t ws_size,
                              hipStream_t stream)
{
    const float* hidden = (const float*)d_in[0];
    const float* Wq = (const float*)d_in[1];
    const float* bq = (const float*)d_in[2];
    const float* Wk = (const float*)d_in[3];
    const float* bk = (const float*)d_in[4];
    const float* Wv = (const float*)d_in[5];
    const float* bv = (const float*)d_in[6];
    const float* Wo = (const float*)d_in[7];
    const float* bo = (const float*)d_in[8];
    const float* relk = (const float*)d_in[9];
    const float* relv = (const float*)d_in[10];

    char* w = (char*)d_ws;
    __bf16* qbw  = (__bf16*)(w);                         // 8 MB  (64,1024,64) bf16
    __bf16* kbw  = (__bf16*)(w + (8u << 20));            // 8 MB
    __bf16* vbw  = (__bf16*)(w + (16u << 20));           // 8 MB
    __bf16* vtbw = (__bf16*)(w + (24u << 20));           // 8 MB  (64,64,1024) bf16
    float*  aow  = (float*)(w + (32u << 20));            // 16 MB (4,1024,1024) fp32
    float*  out  = (float*)d_out;

    qkv_gemm<<<dim3(16, 64, 3), 256, 0, stream>>>(hidden, Wq, Wk, Wv, bq, bk, bv, qbw, kbw, vbw);
    vtrans<<<dim3(16, 64), 256, 0, stream>>>(vbw, vtbw);
    attn_mfma<<<dim3(16, 64), 256, 0, stream>>>((const u16*)qbw, (const u16*)kbw, (const u16*)vtbw,
                                                relk, relv, aow);
    out_gemm<<<dim3(16, 64), 256, 0, stream>>>(aow, Wo, bo, out);
}

// Round 3
// 395.135 us; speedup vs baseline: 4.0564x; 1.3506x over previous
//
#include <hip/hip_runtime.h>
#include <math.h>

#define LQ 1024      // sequence length
#define EE 1024      // embed dim
#define NH 16        // heads
#define HD 64        // head dim
#define KP 3072      // split-GEMM K' (hi*hi | lo*hi | hi*lo)
#define KPA 2048     // A storage cols (hi | lo); third block reuses hi
#define SCALING 0.125f

typedef unsigned short u16;
typedef __bf16 bf16x8 __attribute__((ext_vector_type(8)));
typedef __bf16 bf16x4 __attribute__((ext_vector_type(4)));
typedef float f32x4 __attribute__((ext_vector_type(4)));

#define MFMA16(a, b, c) __builtin_amdgcn_mfma_f32_16x16x32_bf16(a, b, c, 0, 0, 0)

__device__ __forceinline__ void split_bf16(float x, __bf16& h, __bf16& l)
{
    h = (__bf16)x;
    l = (__bf16)(x - (float)h);
}

// ---------------------------------------------------------------------------
// hidden (4096x1024 fp32) -> Ah (4096 x 2048 bf16): [hi | lo]
// ---------------------------------------------------------------------------
__global__ __launch_bounds__(256) void conv_hidden(
    const float* __restrict__ A, __bf16* __restrict__ Ah)
{
    int t = blockIdx.x * 256 + threadIdx.x;
#pragma unroll
    for (int it = 0; it < 4; it++) {
        int f = t + it * 262144;            // float4 index, total 1048576
        int m = f >> 8, c4 = f & 255;
        float4 x = ((const float4*)A)[f];
        float xs[4] = {x.x, x.y, x.z, x.w};
        bf16x4 hv, lv;
#pragma unroll
        for (int j = 0; j < 4; j++) {
            __bf16 h, l; split_bf16(xs[j], h, l);
            hv[j] = h; lv[j] = l;
        }
        __bf16* row = Ah + (size_t)m * KPA;
        *(bf16x4*)(row + c4 * 4)        = hv;
        *(bf16x4*)(row + 1024 + c4 * 4) = lv;
    }
}

// ---------------------------------------------------------------------------
// W (1024x1024 fp32, [k][n]) -> BT (1024 x 3072 bf16, [n][hiT | hiT | loT])
// ---------------------------------------------------------------------------
__global__ __launch_bounds__(256) void conv_w(
    const float* __restrict__ Wq, const float* __restrict__ Wk,
    const float* __restrict__ Wv, const float* __restrict__ Wo,
    __bf16* __restrict__ BTq, __bf16* __restrict__ BTk,
    __bf16* __restrict__ BTv, __bf16* __restrict__ BTo)
{
    const int z = blockIdx.z;
    const float* W = (z == 0) ? Wq : (z == 1) ? Wk : (z == 2) ? Wv : Wo;
    __bf16* BT     = (z == 0) ? BTq : (z == 1) ? BTk : (z == 2) ? BTv : BTo;
    const int n0 = blockIdx.x * 64, k0 = blockIdx.y * 64;
    const int tid = threadIdx.x;
    __shared__ float tbuf[64][65];

#pragma unroll
    for (int rr = 0; rr < 4; rr++) {
        int f = rr * 256 + tid;            // 1024 float4 loads
        int kl = f >> 4, n4 = f & 15;
        float4 x = *(const float4*)&W[(size_t)(k0 + kl) * EE + n0 + n4 * 4];
        tbuf[kl][n4 * 4 + 0] = x.x;
        tbuf[kl][n4 * 4 + 1] = x.y;
        tbuf[kl][n4 * 4 + 2] = x.z;
        tbuf[kl][n4 * 4 + 3] = x.w;
    }
    __syncthreads();
#pragma unroll
    for (int rr = 0; rr < 2; rr++) {
        int f = rr * 256 + tid;            // 512 chunks of 8 along k
        int nl = f >> 3, c8 = f & 7;
        bf16x8 hv, lv;
#pragma unroll
        for (int j = 0; j < 8; j++) {
            __bf16 h, l; split_bf16(tbuf[c8 * 8 + j][nl], h, l);
            hv[j] = h; lv[j] = l;
        }
        __bf16* row = BT + (size_t)(n0 + nl) * KP + k0;
        *(bf16x8*)(row + c8 * 8)        = hv;
        *(bf16x8*)(row + 1024 + c8 * 8) = hv;
        *(bf16x8*)(row + 2048 + c8 * 8) = lv;
    }
}

// ---------------------------------------------------------------------------
// Split-bf16 MFMA GEMM core: 128x128 tile, BK=32, 4 waves, 4x4 16x16x32 frags.
// A: [M][KPA] bf16 (col remap: k'>=2048 -> k'-2048). B: [1024][KP] bf16 (B^T).
// LDS tile layout [k/8][row][8] -> ds_read_b128 frags are 2-way aliasing (free).
// ---------------------------------------------------------------------------
__device__ __forceinline__ void gemm_core(
    const u16* __restrict__ Ab, const u16* __restrict__ Bb,
    int m0, int n0, int tid, f32x4 acc[4][4], u16* As, u16* Bs)
{
    const int lane = tid & 63;
    const int wave = tid >> 6;
    const int wr = wave >> 1, wc = wave & 1;
    const int k2l = lane >> 4, rl = lane & 15;

    for (int k0 = 0; k0 < KP; k0 += 32) {
#pragma unroll
        for (int rr = 0; rr < 2; rr++) {
            int f = rr * 256 + tid;
            int k2 = f >> 7, mm = f & 127;
            int acol = k0 + k2 * 8;
            if (acol >= KPA) acol -= KPA;      // third hi-block reuses cols 0:1024
            __builtin_amdgcn_global_load_lds(Ab + (size_t)(m0 + mm) * KPA + acol,
                                             As + (size_t)(f & ~63) * 8, 16, 0, 0);
        }
#pragma unroll
        for (int rr = 0; rr < 2; rr++) {
            int f = rr * 256 + tid;
            int k2 = f >> 7, nn = f & 127;
            __builtin_amdgcn_global_load_lds(Bb + (size_t)(n0 + nn) * KP + k0 + k2 * 8,
                                             Bs + (size_t)(f & ~63) * 8, 16, 0, 0);
        }
        __syncthreads();

        bf16x8 af[4], bfr[4];
#pragma unroll
        for (int mi = 0; mi < 4; mi++)
            af[mi] = *(const bf16x8*)(As + (size_t)(k2l * 128 + wr * 64 + mi * 16 + rl) * 8);
#pragma unroll
        for (int ni = 0; ni < 4; ni++)
            bfr[ni] = *(const bf16x8*)(Bs + (size_t)(k2l * 128 + wc * 64 + ni * 16 + rl) * 8);
#pragma unroll
        for (int mi = 0; mi < 4; mi++)
#pragma unroll
            for (int ni = 0; ni < 4; ni++)
                acc[mi][ni] = MFMA16(af[mi], bfr[ni], acc[mi][ni]);
        __syncthreads();
    }
}

// ---------------------------------------------------------------------------
// QKV projection via split GEMM; epilogue adds bias (+q scaling), writes bf16
// scattered to (b*H+h, t, d).
// ---------------------------------------------------------------------------
__global__ __launch_bounds__(256) void qkv_mfma(
    const u16* __restrict__ Ah,
    const u16* __restrict__ BTq, const u16* __restrict__ BTk, const u16* __restrict__ BTv,
    const float* __restrict__ bq, const float* __restrict__ bk, const float* __restrict__ bv,
    __bf16* __restrict__ qo, __bf16* __restrict__ ko, __bf16* __restrict__ vo)
{
    const int z = blockIdx.z;
    const u16* Bb      = (z == 0) ? BTq : (z == 1) ? BTk : BTv;
    const float* bias  = (z == 0) ? bq  : (z == 1) ? bk  : bv;
    __bf16* O          = (z == 0) ? qo  : (z == 1) ? ko  : vo;

    __shared__ __attribute__((aligned(16))) u16 As[4096], Bs[4096];
    const int tid = threadIdx.x;
    const int m0 = blockIdx.y * 128, n0 = blockIdx.x * 128;
    f32x4 acc[4][4] = {};
    gemm_core(Ah, Bb, m0, n0, tid, acc, As, Bs);

    const int lane = tid & 63, wave = tid >> 6;
    const int wr = wave >> 1, wc = wave & 1;
    const float qs = (z == 0) ? SCALING : 1.0f;
#pragma unroll
    for (int mi = 0; mi < 4; mi++) {
#pragma unroll
        for (int ni = 0; ni < 4; ni++) {
            int n = n0 + wc * 64 + ni * 16 + (lane & 15);
            int h = n >> 6, d = n & 63;
            float bb = bias[n];
#pragma unroll
            for (int r = 0; r < 4; r++) {
                int m = m0 + wr * 64 + mi * 16 + (lane >> 4) * 4 + r;
                int b = m >> 10, t = m & 1023;
                float v = (acc[mi][ni][r] + bb) * qs;
                O[(size_t)((b * NH + h) * LQ + t) * HD + d] = (__bf16)v;
            }
        }
    }
}

// ---------------------------------------------------------------------------
// Output projection via split GEMM; fp32 output (B, L, E).
// ---------------------------------------------------------------------------
__global__ __launch_bounds__(256) void oproj_mfma(
    const u16* __restrict__ Ao, const u16* __restrict__ BTo,
    const float* __restrict__ bo, float* __restrict__ O)
{
    __shared__ __attribute__((aligned(16))) u16 As[4096], Bs[4096];
    const int tid = threadIdx.x;
    const int m0 = blockIdx.y * 128, n0 = blockIdx.x * 128;
    f32x4 acc[4][4] = {};
    gemm_core(Ao, BTo, m0, n0, tid, acc, As, Bs);

    const int lane = tid & 63, wave = tid >> 6;
    const int wr = wave >> 1, wc = wave & 1;
#pragma unroll
    for (int mi = 0; mi < 4; mi++)
#pragma unroll
        for (int ni = 0; ni < 4; ni++) {
            int n = n0 + wc * 64 + ni * 16 + (lane & 15);
            float bb = bo[n];
#pragma unroll
            for (int r = 0; r < 4; r++) {
                int m = m0 + wr * 64 + mi * 16 + (lane >> 4) * 4 + r;
                O[(size_t)m * EE + n] = acc[mi][ni][r] + bb;
            }
        }
}

// ---------------------------------------------------------------------------
// V transpose: vb[bh][s][d] bf16 -> vtb[bh][d][s] bf16 (per 64-s tile)
// ---------------------------------------------------------------------------
__global__ __launch_bounds__(256) void vtrans(
    const __bf16* __restrict__ vb, __bf16* __restrict__ vtb)
{
    const int bh = blockIdx.y;
    const int s0 = blockIdx.x * 64;
    const int tid = threadIdx.x;
    __shared__ float t[64][65];

#pragma unroll
    for (int rr = 0; rr < 2; rr++) {
        int f = rr * 256 + tid;
        int s = f >> 3, c8 = f & 7;
        bf16x8 v = *(const bf16x8*)(vb + ((size_t)bh * LQ + s0 + s) * HD + c8 * 8);
#pragma unroll
        for (int j = 0; j < 8; j++) t[c8 * 8 + j][s] = (float)v[j];
    }
    __syncthreads();
#pragma unroll
    for (int rr = 0; rr < 2; rr++) {
        int f = rr * 256 + tid;
        int d = f >> 3, c8 = f & 7;
        bf16x8 o;
#pragma unroll
        for (int j = 0; j < 8; j++) o[j] = (__bf16)t[d][c8 * 8 + j];
        *(bf16x8*)(vtb + ((size_t)bh * HD + d) * LQ + s0 + c8 * 8) = o;
    }
}

// ---------------------------------------------------------------------------
// MFMA flash attention with windowed relative-position terms.
// Epilogue writes hi|lo split bf16 rows (stride KPA) for the o-proj GEMM.
// ---------------------------------------------------------------------------
__device__ __forceinline__ bf16x8 ld_frag(const u16* base, int row, int col)
{
    int off = (row * 128 + col * 2) ^ ((row & 7) << 4);
    return *(const bf16x8*)((const char*)base + off);
}

__global__ __launch_bounds__(256) void attn_mfma(
    const u16* __restrict__ qb, const u16* __restrict__ kb,
    const u16* __restrict__ vtb,
    const float* __restrict__ relk, const float* __restrict__ relv,
    __bf16* __restrict__ Ao)
{
    __shared__ __attribute__((aligned(16))) u16 q_lds[64 * 64];
    __shared__ __attribute__((aligned(16))) u16 k_lds[64 * 64];
    __shared__ __attribute__((aligned(16))) u16 v_lds[64 * 64];
    __shared__ __attribute__((aligned(16))) u16 p_lds[64 * 64];  // wave-private 16x64 regions
    __shared__ float R_lds[64 * 9];
    __shared__ float rk_lds[9 * 64];
    __shared__ float rv_lds[9 * 64];

    const int tid  = threadIdx.x;
    const int lane = tid & 63;
    const int wave = tid >> 6;
    const int bh   = blockIdx.y;
    const int q0   = blockIdx.x * 64;

    // ---- stage Q block (64x64 bf16) with inverse-swizzled source ----
#pragma unroll
    for (int rr = 0; rr < 2; rr++) {
        int f = rr * 256 + tid;
        int row = f >> 3, c8 = f & 7;
        const u16* src = qb + ((size_t)bh * LQ + q0 + row) * HD + ((c8 ^ (row & 7)) * 8);
        __builtin_amdgcn_global_load_lds(src, q_lds + (size_t)(f & ~63) * 8, 16, 0, 0);
    }
    for (int u = tid; u < 144; u += 256)
        *(float4*)&rk_lds[u * 4] = *(const float4*)&relk[u * 4];
    for (int u = tid; u < 144; u += 256)
        *(float4*)&rv_lds[u * 4] = *(const float4*)&relv[u * 4];
    __syncthreads();

    // ---- R[t][i] = q[t] . relk[i]  (64 x 9) ----
    for (int j = tid; j < 576; j += 256) {
        int tl = j / 9, i = j - tl * 9;
        float acc = 0.f;
        for (int d = 0; d < 64; d++) {
            int off = (tl * 128 + d * 2) ^ ((tl & 7) << 4);
            float qv = (float)*(const __bf16*)((const char*)q_lds + off);
            acc += qv * rk_lds[i * 64 + d];
        }
        R_lds[tl * 9 + i] = acc;
    }

    bf16x8 qa[2];
    qa[0] = ld_frag(q_lds, wave * 16 + (lane & 15), (lane >> 4) * 8);
    qa[1] = ld_frag(q_lds, wave * 16 + (lane & 15), 32 + (lane >> 4) * 8);

    __syncthreads();

    f32x4 of[4] = {};
    float m_r[4], l_r[4];
#pragma unroll
    for (int r = 0; r < 4; r++) { m_r[r] = -1e30f; l_r[r] = 0.f; }

    const u16* pw = p_lds + wave * 1024;
    u16* pww      = p_lds + wave * 1024;

    for (int s0 = 0; s0 < LQ; s0 += 64) {
#pragma unroll
        for (int rr = 0; rr < 2; rr++) {
            int f = rr * 256 + tid;
            int row = f >> 3, c8 = f & 7;
            const u16* srck = kb + ((size_t)bh * LQ + s0 + row) * HD + ((c8 ^ (row & 7)) * 8);
            __builtin_amdgcn_global_load_lds(srck, k_lds + (size_t)(f & ~63) * 8, 16, 0, 0);
            const u16* srcv = vtb + ((size_t)bh * HD + row) * LQ + s0 + ((c8 ^ (row & 7)) * 8);
            __builtin_amdgcn_global_load_lds(srcv, v_lds + (size_t)(f & ~63) * 8, 16, 0, 0);
        }
        __syncthreads();

        // ---- S = Q @ K^T ----
        f32x4 sf[4] = {};
#pragma unroll
        for (int sub = 0; sub < 4; sub++) {
#pragma unroll
            for (int kk = 0; kk < 2; kk++) {
                bf16x8 kf = ld_frag(k_lds, sub * 16 + (lane & 15), kk * 32 + (lane >> 4) * 8);
                sf[sub] = MFMA16(qa[kk], kf, sf[sub]);
            }
        }

        int drel = s0 - q0;
        bool diag = (drel == -64) || (drel == 0) || (drel == 64);
        if (diag) {
#pragma unroll
            for (int sub = 0; sub < 4; sub++) {
#pragma unroll
                for (int r = 0; r < 4; r++) {
                    int tl = wave * 16 + (lane >> 4) * 4 + r;
                    int s  = s0 + sub * 16 + (lane & 15);
                    int i  = s - (q0 + tl) + 4;
                    if ((unsigned)i <= 8u) sf[sub][r] += R_lds[tl * 9 + i];
                }
            }
        }

        // ---- online softmax ----
        float tmax[4];
#pragma unroll
        for (int r = 0; r < 4; r++) {
            float m0 = fmaxf(fmaxf(sf[0][r], sf[1][r]), fmaxf(sf[2][r], sf[3][r]));
#pragma unroll
            for (int msk = 8; msk >= 1; msk >>= 1) m0 = fmaxf(m0, __shfl_xor(m0, msk, 64));
            tmax[r] = m0;
        }
#pragma unroll
        for (int r = 0; r < 4; r++) {
            float mn = fmaxf(m_r[r], tmax[r]);
            float sc = __expf(m_r[r] - mn);
            m_r[r] = mn;
            l_r[r] *= sc;
#pragma unroll
            for (int sub = 0; sub < 4; sub++) of[sub][r] *= sc;
        }
#pragma unroll
        for (int sub = 0; sub < 4; sub++) {
#pragma unroll
            for (int r = 0; r < 4; r++) {
                float p = __expf(sf[sub][r] - m_r[r]);
                l_r[r] += p;
                int q = (lane >> 4) * 4 + r;
                int off = (q * 128 + (sub * 16 + (lane & 15)) * 2) ^ ((q & 7) << 4);
                *(__bf16*)((char*)pww + off) = (__bf16)p;
            }
        }

        // ---- O += P @ V ----
#pragma unroll
        for (int kk = 0; kk < 2; kk++) {
            bf16x8 pa = ld_frag(pw, lane & 15, kk * 32 + (lane >> 4) * 8);
#pragma unroll
            for (int dsub = 0; dsub < 4; dsub++) {
                bf16x8 vf = ld_frag(v_lds, dsub * 16 + (lane & 15), kk * 32 + (lane >> 4) * 8);
                of[dsub] = MFMA16(pa, vf, of[dsub]);
            }
        }

        if (diag) {
#pragma unroll
            for (int r = 0; r < 4; r++) {
                int q  = (lane >> 4) * 4 + r;
                int tl = wave * 16 + q;
#pragma unroll
                for (int i = 0; i < 9; i++) {
                    int s  = q0 + tl + i - 4;
                    int sl = s - s0;
                    if ((unsigned)sl < 64u) {
                        int off = (q * 128 + sl * 2) ^ ((q & 7) << 4);
                        float p = (float)*(const __bf16*)((const char*)pww + off);
#pragma unroll
                        for (int dsub = 0; dsub < 4; dsub++)
                            of[dsub][r] += p * rv_lds[i * 64 + dsub * 16 + (lane & 15)];
                    }
                }
            }
        }
        __syncthreads();
    }

    // ---- final normalize + write hi|lo split rows (stride KPA) ----
#pragma unroll
    for (int r = 0; r < 4; r++) {
        float s = l_r[r];
#pragma unroll
        for (int msk = 8; msk >= 1; msk >>= 1) s += __shfl_xor(s, msk, 64);
        l_r[r] = 1.0f / s;
    }
    const int b = bh >> 4, h = bh & 15;
#pragma unroll
    for (int dsub = 0; dsub < 4; dsub++) {
#pragma unroll
        for (int r = 0; r < 4; r++) {
            int t = q0 + wave * 16 + (lane >> 4) * 4 + r;
            int e = h * 64 + dsub * 16 + (lane & 15);
            float v = of[dsub][r] * l_r[r];
            __bf16 hh, ll; split_bf16(v, hh, ll);
            __bf16* row = Ao + (size_t)(b * LQ + t) * KPA;
            row[e]        = hh;
            row[1024 + e] = ll;
        }
    }
}

// ---------------------------------------------------------------------------
extern "C" void kernel_launch(void* const* d_in, const int* in_sizes, int n_in,
                              void* d_out, int out_size, void* d_ws, size_t ws_size,
                              hipStream_t stream)
{
    const float* hidden = (const float*)d_in[0];
    const float* Wq = (const float*)d_in[1];
    const float* bq = (const float*)d_in[2];
    const float* Wk = (const float*)d_in[3];
    const float* bk = (const float*)d_in[4];
    const float* Wv = (const float*)d_in[5];
    const float* bv = (const float*)d_in[6];
    const float* Wo = (const float*)d_in[7];
    const float* bo = (const float*)d_in[8];
    const float* relk = (const float*)d_in[9];
    const float* relv = (const float*)d_in[10];

    char* w = (char*)d_ws;
    __bf16* Ah   = (__bf16*)(w);                    // 16 MB (4096 x 2048) — aliased with Ao
    __bf16* Ao   = (__bf16*)(w);                    //        (attn writes after qkv reads)
    __bf16* BTq  = (__bf16*)(w + (16u << 20));      // 6 MB  (1024 x 3072)
    __bf16* BTk  = (__bf16*)(w + (22u << 20));      // 6 MB
    __bf16* BTv  = (__bf16*)(w + (28u << 20));      // 6 MB
    __bf16* BTo  = (__bf16*)(w + (34u << 20));      // 6 MB
    __bf16* qbw  = (__bf16*)(w + (40u << 20));      // 8 MB  (64,1024,64)
    __bf16* kbw  = (__bf16*)(w + (48u << 20));      // 8 MB
    __bf16* vbw  = (__bf16*)(w + (56u << 20));      // 8 MB
    __bf16* vtbw = (__bf16*)(w + (64u << 20));      // 8 MB  (64,64,1024)  -> 72 MB total
    float*  out  = (float*)d_out;

    conv_hidden<<<1024, 256, 0, stream>>>(hidden, Ah);
    conv_w<<<dim3(16, 16, 4), 256, 0, stream>>>(Wq, Wk, Wv, Wo, BTq, BTk, BTv, BTo);
    qkv_mfma<<<dim3(8, 32, 3), 256, 0, stream>>>((const u16*)Ah,
        (const u16*)BTq, (const u16*)BTk, (const u16*)BTv, bq, bk, bv, qbw, kbw, vbw);
    vtrans<<<dim3(16, 64), 256, 0, stream>>>(vbw, vtbw);
    attn_mfma<<<dim3(16, 64), 256, 0, stream>>>((const u16*)qbw, (const u16*)kbw,
        (const u16*)vtbw, relk, relv, Ao);
    oproj_mfma<<<dim3(8, 32), 256, 0, stream>>>((const u16*)Ao, (const u16*)BTo, bo, out);
}

// Round 5
// 362.459 us; speedup vs baseline: 4.4221x; 1.0902x over previous
//
#include <hip/hip_runtime.h>
#include <math.h>

#define LQ 1024      // sequence length
#define EE 1024      // embed dim
#define NH 16        // heads
#define HD 64        // head dim
#define KP 3072      // split-GEMM K' (hi*hi | lo*hi | hi*lo)
#define KPA 2048     // A storage cols (hi | lo); third block reuses hi
#define SCALING 0.125f

typedef unsigned short u16;
typedef __bf16 bf16x8 __attribute__((ext_vector_type(8)));
typedef __bf16 bf16x4 __attribute__((ext_vector_type(4)));
typedef float f32x4 __attribute__((ext_vector_type(4)));

#define MFMA16(a, b, c) __builtin_amdgcn_mfma_f32_16x16x32_bf16(a, b, c, 0, 0, 0)

__device__ __forceinline__ void split_bf16(float x, __bf16& h, __bf16& l)
{
    h = (__bf16)x;
    l = (__bf16)(x - (float)h);
}

// ---------------------------------------------------------------------------
// hidden (4096x1024 fp32) -> Ah (4096 x 2048 bf16): [hi | lo]
// ---------------------------------------------------------------------------
__global__ __launch_bounds__(256) void conv_hidden(
    const float* __restrict__ A, __bf16* __restrict__ Ah)
{
    int t = blockIdx.x * 256 + threadIdx.x;
#pragma unroll
    for (int it = 0; it < 4; it++) {
        int f = t + it * 262144;            // float4 index, total 1048576
        int m = f >> 8, c4 = f & 255;
        float4 x = ((const float4*)A)[f];
        float xs[4] = {x.x, x.y, x.z, x.w};
        bf16x4 hv, lv;
#pragma unroll
        for (int j = 0; j < 4; j++) {
            __bf16 h, l; split_bf16(xs[j], h, l);
            hv[j] = h; lv[j] = l;
        }
        __bf16* row = Ah + (size_t)m * KPA;
        *(bf16x4*)(row + c4 * 4)        = hv;
        *(bf16x4*)(row + 1024 + c4 * 4) = lv;
    }
}

// ---------------------------------------------------------------------------
// W (1024x1024 fp32, [k][n]) -> BT (1024 x 3072 bf16, [n][hiT | hiT | loT])
// ---------------------------------------------------------------------------
__global__ __launch_bounds__(256) void conv_w(
    const float* __restrict__ Wq, const float* __restrict__ Wk,
    const float* __restrict__ Wv, const float* __restrict__ Wo,
    __bf16* __restrict__ BTq, __bf16* __restrict__ BTk,
    __bf16* __restrict__ BTv, __bf16* __restrict__ BTo)
{
    const int z = blockIdx.z;
    const float* W = (z == 0) ? Wq : (z == 1) ? Wk : (z == 2) ? Wv : Wo;
    __bf16* BT     = (z == 0) ? BTq : (z == 1) ? BTk : (z == 2) ? BTv : BTo;
    const int n0 = blockIdx.x * 64, k0 = blockIdx.y * 64;
    const int tid = threadIdx.x;
    __shared__ float tbuf[64][65];

#pragma unroll
    for (int rr = 0; rr < 4; rr++) {
        int f = rr * 256 + tid;            // 1024 float4 loads
        int kl = f >> 4, n4 = f & 15;
        float4 x = *(const float4*)&W[(size_t)(k0 + kl) * EE + n0 + n4 * 4];
        tbuf[kl][n4 * 4 + 0] = x.x;
        tbuf[kl][n4 * 4 + 1] = x.y;
        tbuf[kl][n4 * 4 + 2] = x.z;
        tbuf[kl][n4 * 4 + 3] = x.w;
    }
    __syncthreads();
#pragma unroll
    for (int rr = 0; rr < 2; rr++) {
        int f = rr * 256 + tid;            // 512 chunks of 8 along k
        int nl = f >> 3, c8 = f & 7;
        bf16x8 hv, lv;
#pragma unroll
        for (int j = 0; j < 8; j++) {
            __bf16 h, l; split_bf16(tbuf[c8 * 8 + j][nl], h, l);
            hv[j] = h; lv[j] = l;
        }
        __bf16* row = BT + (size_t)(n0 + nl) * KP + k0;
        *(bf16x8*)(row + c8 * 8)        = hv;
        *(bf16x8*)(row + 1024 + c8 * 8) = hv;
        *(bf16x8*)(row + 2048 + c8 * 8) = lv;
    }
}

// ---------------------------------------------------------------------------
// Split-bf16 MFMA GEMM core, 2-phase double-buffered (T3 minimum recipe):
//   STAGE(buf0, t=0); barrier;
//   loop: STAGE(buf^1, t+1); ds_read+MFMA buf; barrier (drains vmcnt); flip.
// 128x128 tile, BK=32, 4 waves, 4x4 16x16x32 frags.
// A: [M][KPA] bf16 (col remap: k'>=2048 -> k'-2048). B: [Nrows][KP] bf16 (B^T).
// LDS tile layout [k/8][row][8].
// ---------------------------------------------------------------------------
__device__ __forceinline__ void stage_tile(
    const u16* __restrict__ Ab, const u16* __restrict__ Bb,
    int m0, int nrow0, int k0, int tid, u16* As, u16* Bs)
{
#pragma unroll
    for (int rr = 0; rr < 2; rr++) {
        int f = rr * 256 + tid;
        int k2 = f >> 7, mm = f & 127;
        int acol = k0 + k2 * 8;
        if (acol >= KPA) acol -= KPA;      // third hi-block reuses cols 0:1024
        __builtin_amdgcn_global_load_lds(Ab + (size_t)(m0 + mm) * KPA + acol,
                                         As + (size_t)(f & ~63) * 8, 16, 0, 0);
    }
#pragma unroll
    for (int rr = 0; rr < 2; rr++) {
        int f = rr * 256 + tid;
        int k2 = f >> 7, nn = f & 127;
        __builtin_amdgcn_global_load_lds(Bb + (size_t)(nrow0 + nn) * KP + k0 + k2 * 8,
                                         Bs + (size_t)(f & ~63) * 8, 16, 0, 0);
    }
}

__device__ __forceinline__ void gemm_core_db(
    const u16* __restrict__ Ab, const u16* __restrict__ Bb,
    int m0, int nrow0, int tid, f32x4 acc[4][4],
    u16* As0, u16* Bs0, u16* As1, u16* Bs1)
{
    const int lane = tid & 63;
    const int wave = tid >> 6;
    const int wr = wave >> 1, wc = wave & 1;
    const int k2l = lane >> 4, rl = lane & 15;

    stage_tile(Ab, Bb, m0, nrow0, 0, tid, As0, Bs0);
    __syncthreads();                        // drains vmcnt(0) + barrier

    int cur = 0;
    for (int k0 = 0; k0 < KP; k0 += 32) {
        u16* Ac = cur ? As1 : As0;
        u16* Bc = cur ? Bs1 : Bs0;
        if (k0 + 32 < KP)                   // prefetch next tile into other buffer
            stage_tile(Ab, Bb, m0, nrow0, k0 + 32, tid,
                       cur ? As0 : As1, cur ? Bs0 : Bs1);

        bf16x8 af[4], bfr[4];
#pragma unroll
        for (int mi = 0; mi < 4; mi++)
            af[mi] = *(const bf16x8*)(Ac + (size_t)(k2l * 128 + wr * 64 + mi * 16 + rl) * 8);
#pragma unroll
        for (int ni = 0; ni < 4; ni++)
            bfr[ni] = *(const bf16x8*)(Bc + (size_t)(k2l * 128 + wc * 64 + ni * 16 + rl) * 8);
#pragma unroll
        for (int mi = 0; mi < 4; mi++)
#pragma unroll
            for (int ni = 0; ni < 4; ni++)
                acc[mi][ni] = MFMA16(af[mi], bfr[ni], acc[mi][ni]);

        __syncthreads();                    // waits prefetch (vmcnt 0) + barrier
        cur ^= 1;
    }
}

// ---------------------------------------------------------------------------
// Fused QKV projection via split GEMM: one dispatch, N=3072 over BTq|BTk|BTv
// (contiguous). Epilogue adds bias (+q scaling), writes bf16 per-head layout.
// Grid: 768 blocks 1-D, bijective XCD swizzle (768 % 8 == 0).
// ---------------------------------------------------------------------------
__global__ __launch_bounds__(256) void qkv_mfma(
    const u16* __restrict__ Ah, const u16* __restrict__ BTall,
    const float* __restrict__ bq, const float* __restrict__ bk, const float* __restrict__ bv,
    __bf16* __restrict__ qo, __bf16* __restrict__ ko, __bf16* __restrict__ vo)
{
    const int wg  = blockIdx.x;
    const int swz = (wg & 7) * 96 + (wg >> 3);   // 768/8 = 96 per XCD
    const int bx  = swz % 24, by = swz / 24;

    __shared__ __attribute__((aligned(16))) u16 As[2][4096], Bs[2][4096];
    const int tid = threadIdx.x;
    const int m0 = by * 128;
    const int nrow0 = bx * 128;                  // row into concatenated BT
    f32x4 acc[4][4] = {};
    gemm_core_db(Ah, BTall, m0, nrow0, tid, acc, As[0], Bs[0], As[1], Bs[1]);

    const int z   = bx >> 3;                     // 0:q 1:k 2:v
    const int n0l = (bx & 7) * 128;              // local n within 1024
    const float* bias = (z == 0) ? bq : (z == 1) ? bk : bv;
    __bf16* O         = (z == 0) ? qo : (z == 1) ? ko : vo;
    const float qs    = (z == 0) ? SCALING : 1.0f;

    const int lane = tid & 63, wave = tid >> 6;
    const int wr = wave >> 1, wc = wave & 1;
#pragma unroll
    for (int mi = 0; mi < 4; mi++) {
#pragma unroll
        for (int ni = 0; ni < 4; ni++) {
            int n = n0l + wc * 64 + ni * 16 + (lane & 15);
            int h = n >> 6, d = n & 63;
            float bb = bias[n];
#pragma unroll
            for (int r = 0; r < 4; r++) {
                int m = m0 + wr * 64 + mi * 16 + (lane >> 4) * 4 + r;
                int b = m >> 10, t = m & 1023;
                float v = (acc[mi][ni][r] + bb) * qs;
                O[(size_t)((b * NH + h) * LQ + t) * HD + d] = (__bf16)v;
            }
        }
    }
}

// ---------------------------------------------------------------------------
// Output projection via split GEMM; fp32 output (B, L, E).
// ---------------------------------------------------------------------------
__global__ __launch_bounds__(256) void oproj_mfma(
    const u16* __restrict__ Ao, const u16* __restrict__ BTo,
    const float* __restrict__ bo, float* __restrict__ O)
{
    const int wg  = blockIdx.x;
    const int swz = (wg & 7) * 32 + (wg >> 3);   // 256/8 = 32 per XCD
    const int bx  = swz % 8, by = swz / 8;

    __shared__ __attribute__((aligned(16))) u16 As[2][4096], Bs[2][4096];
    const int tid = threadIdx.x;
    const int m0 = by * 128, n0 = bx * 128;
    f32x4 acc[4][4] = {};
    gemm_core_db(Ao, BTo, m0, n0, tid, acc, As[0], Bs[0], As[1], Bs[1]);

    const int lane = tid & 63, wave = tid >> 6;
    const int wr = wave >> 1, wc = wave & 1;
#pragma unroll
    for (int mi = 0; mi < 4; mi++)
#pragma unroll
        for (int ni = 0; ni < 4; ni++) {
            int n = n0 + wc * 64 + ni * 16 + (lane & 15);
            float bb = bo[n];
#pragma unroll
            for (int r = 0; r < 4; r++) {
                int m = m0 + wr * 64 + mi * 16 + (lane >> 4) * 4 + r;
                O[(size_t)m * EE + n] = acc[mi][ni][r] + bb;
            }
        }
}

// ---------------------------------------------------------------------------
// V transpose: vb[bh][s][d] bf16 -> vtb[bh][d][s] bf16 (per 64-s tile)
// ---------------------------------------------------------------------------
__global__ __launch_bounds__(256) void vtrans(
    const __bf16* __restrict__ vb, __bf16* __restrict__ vtb)
{
    const int bh = blockIdx.y;
    const int s0 = blockIdx.x * 64;
    const int tid = threadIdx.x;
    __shared__ float t[64][65];

#pragma unroll
    for (int rr = 0; rr < 2; rr++) {
        int f = rr * 256 + tid;
        int s = f >> 3, c8 = f & 7;
        bf16x8 v = *(const bf16x8*)(vb + ((size_t)bh * LQ + s0 + s) * HD + c8 * 8);
#pragma unroll
        for (int j = 0; j < 8; j++) t[c8 * 8 + j][s] = (float)v[j];
    }
    __syncthreads();
#pragma unroll
    for (int rr = 0; rr < 2; rr++) {
        int f = rr * 256 + tid;
        int d = f >> 3, c8 = f & 7;
        bf16x8 o;
#pragma unroll
        for (int j = 0; j < 8; j++) o[j] = (__bf16)t[d][c8 * 8 + j];
        *(bf16x8*)(vtb + ((size_t)bh * HD + d) * LQ + s0 + c8 * 8) = o;
    }
}

// ---------------------------------------------------------------------------
// MFMA flash attention with windowed relative-position terms.
// Epilogue writes hi|lo split bf16 rows (stride KPA) for the o-proj GEMM.
// ---------------------------------------------------------------------------
__device__ __forceinline__ bf16x8 ld_frag(const u16* base, int row, int col)
{
    int off = (row * 128 + col * 2) ^ ((row & 7) << 4);
    return *(const bf16x8*)((const char*)base + off);
}

__global__ __launch_bounds__(256) void attn_mfma(
    const u16* __restrict__ qb, const u16* __restrict__ kb,
    const u16* __restrict__ vtb,
    const float* __restrict__ relk, const float* __restrict__ relv,
    __bf16* __restrict__ Ao)
{
    __shared__ __attribute__((aligned(16))) u16 q_lds[64 * 64];
    __shared__ __attribute__((aligned(16))) u16 k_lds[64 * 64];
    __shared__ __attribute__((aligned(16))) u16 v_lds[64 * 64];
    __shared__ __attribute__((aligned(16))) u16 p_lds[64 * 64];  // wave-private 16x64 regions
    __shared__ float R_lds[64 * 9];
    __shared__ float rk_lds[9 * 64];
    __shared__ float rv_lds[9 * 64];

    const int tid  = threadIdx.x;
    const int lane = tid & 63;
    const int wave = tid >> 6;
    const int bh   = blockIdx.y;
    const int q0   = blockIdx.x * 64;

    // ---- stage Q block (64x64 bf16) with inverse-swizzled source ----
#pragma unroll
    for (int rr = 0; rr < 2; rr++) {
        int f = rr * 256 + tid;
        int row = f >> 3, c8 = f & 7;
        const u16* src = qb + ((size_t)bh * LQ + q0 + row) * HD + ((c8 ^ (row & 7)) * 8);
        __builtin_amdgcn_global_load_lds(src, q_lds + (size_t)(f & ~63) * 8, 16, 0, 0);
    }
    for (int u = tid; u < 144; u += 256)
        *(float4*)&rk_lds[u * 4] = *(const float4*)&relk[u * 4];
    for (int u = tid; u < 144; u += 256)
        *(float4*)&rv_lds[u * 4] = *(const float4*)&relv[u * 4];
    __syncthreads();

    // ---- R[t][i] = q[t] . relk[i]  (64 x 9) ----
    for (int j = tid; j < 576; j += 256) {
        int tl = j / 9, i = j - tl * 9;
        float acc = 0.f;
        for (int d = 0; d < 64; d++) {
            int off = (tl * 128 + d * 2) ^ ((tl & 7) << 4);
            float qv = (float)*(const __bf16*)((const char*)q_lds + off);
            acc += qv * rk_lds[i * 64 + d];
        }
        R_lds[tl * 9 + i] = acc;
    }

    bf16x8 qa[2];
    qa[0] = ld_frag(q_lds, wave * 16 + (lane & 15), (lane >> 4) * 8);
    qa[1] = ld_frag(q_lds, wave * 16 + (lane & 15), 32 + (lane >> 4) * 8);

    __syncthreads();

    f32x4 of[4] = {};
    float m_r[4], l_r[4];
#pragma unroll
    for (int r = 0; r < 4; r++) { m_r[r] = -1e30f; l_r[r] = 0.f; }

    const u16* pw = p_lds + wave * 1024;
    u16* pww      = p_lds + wave * 1024;

    for (int s0 = 0; s0 < LQ; s0 += 64) {
#pragma unroll
        for (int rr = 0; rr < 2; rr++) {
            int f = rr * 256 + tid;
            int row = f >> 3, c8 = f & 7;
            const u16* srck = kb + ((size_t)bh * LQ + s0 + row) * HD + ((c8 ^ (row & 7)) * 8);
            __builtin_amdgcn_global_load_lds(srck, k_lds + (size_t)(f & ~63) * 8, 16, 0, 0);
            const u16* srcv = vtb + ((size_t)bh * HD + row) * LQ + s0 + ((c8 ^ (row & 7)) * 8);
            __builtin_amdgcn_global_load_lds(srcv, v_lds + (size_t)(f & ~63) * 8, 16, 0, 0);
        }
        __syncthreads();

        // ---- S = Q @ K^T ----
        f32x4 sf[4] = {};
#pragma unroll
        for (int sub = 0; sub < 4; sub++) {
#pragma unroll
            for (int kk = 0; kk < 2; kk++) {
                bf16x8 kf = ld_frag(k_lds, sub * 16 + (lane & 15), kk * 32 + (lane >> 4) * 8);
                sf[sub] = MFMA16(qa[kk], kf, sf[sub]);
            }
        }

        int drel = s0 - q0;
        bool diag = (drel == -64) || (drel == 0) || (drel == 64);
        if (diag) {
#pragma unroll
            for (int sub = 0; sub < 4; sub++) {
#pragma unroll
                for (int r = 0; r < 4; r++) {
                    int tl = wave * 16 + (lane >> 4) * 4 + r;
                    int s  = s0 + sub * 16 + (lane & 15);
                    int i  = s - (q0 + tl) + 4;
                    if ((unsigned)i <= 8u) sf[sub][r] += R_lds[tl * 9 + i];
                }
            }
        }

        // ---- online softmax ----
        float tmax[4];
#pragma unroll
        for (int r = 0; r < 4; r++) {
            float m0 = fmaxf(fmaxf(sf[0][r], sf[1][r]), fmaxf(sf[2][r], sf[3][r]));
#pragma unroll
            for (int msk = 8; msk >= 1; msk >>= 1) m0 = fmaxf(m0, __shfl_xor(m0, msk, 64));
            tmax[r] = m0;
        }
#pragma unroll
        for (int r = 0; r < 4; r++) {
            float mn = fmaxf(m_r[r], tmax[r]);
            float sc = __expf(m_r[r] - mn);
            m_r[r] = mn;
            l_r[r] *= sc;
#pragma unroll
            for (int sub = 0; sub < 4; sub++) of[sub][r] *= sc;
        }
#pragma unroll
        for (int sub = 0; sub < 4; sub++) {
#pragma unroll
            for (int r = 0; r < 4; r++) {
                float p = __expf(sf[sub][r] - m_r[r]);
                l_r[r] += p;
                int q = (lane >> 4) * 4 + r;
                int off = (q * 128 + (sub * 16 + (lane & 15)) * 2) ^ ((q & 7) << 4);
                *(__bf16*)((char*)pww + off) = (__bf16)p;
            }
        }

        // ---- O += P @ V ----
#pragma unroll
        for (int kk = 0; kk < 2; kk++) {
            bf16x8 pa = ld_frag(pw, lane & 15, kk * 32 + (lane >> 4) * 8);
#pragma unroll
            for (int dsub = 0; dsub < 4; dsub++) {
                bf16x8 vf = ld_frag(v_lds, dsub * 16 + (lane & 15), kk * 32 + (lane >> 4) * 8);
                of[dsub] = MFMA16(pa, vf, of[dsub]);
            }
        }

        if (diag) {
#pragma unroll
            for (int r = 0; r < 4; r++) {
                int q  = (lane >> 4) * 4 + r;
                int tl = wave * 16 + q;
#pragma unroll
                for (int i = 0; i < 9; i++) {
                    int s  = q0 + tl + i - 4;
                    int sl = s - s0;
                    if ((unsigned)sl < 64u) {
                        int off = (q * 128 + sl * 2) ^ ((q & 7) << 4);
                        float p = (float)*(const __bf16*)((const char*)pww + off);
#pragma unroll
                        for (int dsub = 0; dsub < 4; dsub++)
                            of[dsub][r] += p * rv_lds[i * 64 + dsub * 16 + (lane & 15)];
                    }
                }
            }
        }
        __syncthreads();
    }

    // ---- final normalize + write hi|lo split rows (stride KPA) ----
#pragma unroll
    for (int r = 0; r < 4; r++) {
        float s = l_r[r];
#pragma unroll
        for (int msk = 8; msk >= 1; msk >>= 1) s += __shfl_xor(s, msk, 64);
        l_r[r] = 1.0f / s;
    }
    const int b = bh >> 4, h = bh & 15;
#pragma unroll
    for (int dsub = 0; dsub < 4; dsub++) {
#pragma unroll
        for (int r = 0; r < 4; r++) {
            int t = q0 + wave * 16 + (lane >> 4) * 4 + r;
            int e = h * 64 + dsub * 16 + (lane & 15);
            float v = of[dsub][r] * l_r[r];
            __bf16 hh, ll; split_bf16(v, hh, ll);
            __bf16* row = Ao + (size_t)(b * LQ + t) * KPA;
            row[e]        = hh;
            row[1024 + e] = ll;
        }
    }
}

// ---------------------------------------------------------------------------
extern "C" void kernel_launch(void* const* d_in, const int* in_sizes, int n_in,
                              void* d_out, int out_size, void* d_ws, size_t ws_size,
                              hipStream_t stream)
{
    const float* hidden = (const float*)d_in[0];
    const float* Wq = (const float*)d_in[1];
    const float* bq = (const float*)d_in[2];
    const float* Wk = (const float*)d_in[3];
    const float* bk = (const float*)d_in[4];
    const float* Wv = (const float*)d_in[5];
    const float* bv = (const float*)d_in[6];
    const float* Wo = (const float*)d_in[7];
    const float* bo = (const float*)d_in[8];
    const float* relk = (const float*)d_in[9];
    const float* relv = (const float*)d_in[10];

    char* w = (char*)d_ws;
    // Workspace layout (no trailing backslashes in these comments!):
    // Ah/Ao 16 MB at 0; BTq 16M..22M, BTk 22M..28M, BTv 28M..34M (contiguous
    // N=3072 for the fused QKV GEMM); BTo 34M..40M; qbw/kbw/vbw/vtbw 8 MB each.
    __bf16* Ah   = (__bf16*)(w);
    __bf16* Ao   = (__bf16*)(w);
    __bf16* BTq  = (__bf16*)(w + (16u << 20));
    __bf16* BTk  = (__bf16*)(w + (22u << 20));
    __bf16* BTv  = (__bf16*)(w + (28u << 20));
    __bf16* BTo  = (__bf16*)(w + (34u << 20));
    __bf16* qbw  = (__bf16*)(w + (40u << 20));
    __bf16* kbw  = (__bf16*)(w + (48u << 20));
    __bf16* vbw  = (__bf16*)(w + (56u << 20));
    __bf16* vtbw = (__bf16*)(w + (64u << 20));
    float*  out  = (float*)d_out;

    conv_hidden<<<1024, 256, 0, stream>>>(hidden, Ah);
    conv_w<<<dim3(16, 16, 4), 256, 0, stream>>>(Wq, Wk, Wv, Wo, BTq, BTk, BTv, BTo);
    qkv_mfma<<<768, 256, 0, stream>>>((const u16*)Ah, (const u16*)BTq,
                                      bq, bk, bv, qbw, kbw, vbw);
    vtrans<<<dim3(16, 64), 256, 0, stream>>>(vbw, vtbw);
    attn_mfma<<<dim3(16, 64), 256, 0, stream>>>((const u16*)qbw, (const u16*)kbw,
        (const u16*)vtbw, relk, relv, Ao);
    oproj_mfma<<<256, 256, 0, stream>>>((const u16*)Ao, (const u16*)BTo, bo, out);
}

// Round 6
// 350.495 us; speedup vs baseline: 4.5730x; 1.0341x over previous
//
#include <hip/hip_runtime.h>
#include <math.h>

#define LQ 1024      // sequence length
#define EE 1024      // embed dim
#define NH 16        // heads
#define HD 64        // head dim
#define KP 3072      // split-GEMM K' (hi*hi | lo*hi | hi*lo)
#define KPA 2048     // A storage cols (hi | lo); third block reuses hi
#define SCALING 0.125f

typedef unsigned short u16;
typedef __bf16 bf16x8 __attribute__((ext_vector_type(8)));
typedef __bf16 bf16x4 __attribute__((ext_vector_type(4)));
typedef float f32x4 __attribute__((ext_vector_type(4)));

#define MFMA16(a, b, c) __builtin_amdgcn_mfma_f32_16x16x32_bf16(a, b, c, 0, 0, 0)

__device__ __forceinline__ void split_bf16(float x, __bf16& h, __bf16& l)
{
    h = (__bf16)x;
    l = (__bf16)(x - (float)h);
}

// ---------------------------------------------------------------------------
// hidden (4096x1024 fp32) -> Ah (4096 x 2048 bf16): [hi | lo]
// ---------------------------------------------------------------------------
__global__ __launch_bounds__(256) void conv_hidden(
    const float* __restrict__ A, __bf16* __restrict__ Ah)
{
    int t = blockIdx.x * 256 + threadIdx.x;
#pragma unroll
    for (int it = 0; it < 4; it++) {
        int f = t + it * 262144;            // float4 index, total 1048576
        int m = f >> 8, c4 = f & 255;
        float4 x = ((const float4*)A)[f];
        float xs[4] = {x.x, x.y, x.z, x.w};
        bf16x4 hv, lv;
#pragma unroll
        for (int j = 0; j < 4; j++) {
            __bf16 h, l; split_bf16(xs[j], h, l);
            hv[j] = h; lv[j] = l;
        }
        __bf16* row = Ah + (size_t)m * KPA;
        *(bf16x4*)(row + c4 * 4)        = hv;
        *(bf16x4*)(row + 1024 + c4 * 4) = lv;
    }
}

// ---------------------------------------------------------------------------
// W (1024x1024 fp32, [k][n]) -> BT (1024 x 3072 bf16, [n][hiT | hiT | loT])
// ---------------------------------------------------------------------------
__global__ __launch_bounds__(256) void conv_w(
    const float* __restrict__ Wq, const float* __restrict__ Wk,
    const float* __restrict__ Wv, const float* __restrict__ Wo,
    __bf16* __restrict__ BTq, __bf16* __restrict__ BTk,
    __bf16* __restrict__ BTv, __bf16* __restrict__ BTo)
{
    const int z = blockIdx.z;
    const float* W = (z == 0) ? Wq : (z == 1) ? Wk : (z == 2) ? Wv : Wo;
    __bf16* BT     = (z == 0) ? BTq : (z == 1) ? BTk : (z == 2) ? BTv : BTo;
    const int n0 = blockIdx.x * 64, k0 = blockIdx.y * 64;
    const int tid = threadIdx.x;
    __shared__ float tbuf[64][65];

#pragma unroll
    for (int rr = 0; rr < 4; rr++) {
        int f = rr * 256 + tid;            // 1024 float4 loads
        int kl = f >> 4, n4 = f & 15;
        float4 x = *(const float4*)&W[(size_t)(k0 + kl) * EE + n0 + n4 * 4];
        tbuf[kl][n4 * 4 + 0] = x.x;
        tbuf[kl][n4 * 4 + 1] = x.y;
        tbuf[kl][n4 * 4 + 2] = x.z;
        tbuf[kl][n4 * 4 + 3] = x.w;
    }
    __syncthreads();
#pragma unroll
    for (int rr = 0; rr < 2; rr++) {
        int f = rr * 256 + tid;            // 512 chunks of 8 along k
        int nl = f >> 3, c8 = f & 7;
        bf16x8 hv, lv;
#pragma unroll
        for (int j = 0; j < 8; j++) {
            __bf16 h, l; split_bf16(tbuf[c8 * 8 + j][nl], h, l);
            hv[j] = h; lv[j] = l;
        }
        __bf16* row = BT + (size_t)(n0 + nl) * KP + k0;
        *(bf16x8*)(row + c8 * 8)        = hv;
        *(bf16x8*)(row + 1024 + c8 * 8) = hv;
        *(bf16x8*)(row + 2048 + c8 * 8) = lv;
    }
}

// ---------------------------------------------------------------------------
// Fused QKV projection: 256x256 tile, BK=64, 8 waves (512 thr), 2-phase dbuf.
// A: [4096][KPA] bf16 (col remap k'>=2048 -> k'-2048). B: [3072][KP] (B^T).
// LDS per buffer: [k2 0..7][row 0..255][8] u16 = 32 KB each for A and B.
// Grid 192 = 16 by x 12 bx, bijective XCD swizzle (2 m-bands x 12 n per XCD).
// ---------------------------------------------------------------------------
__device__ __forceinline__ void stage256(
    const u16* __restrict__ Ab, const u16* __restrict__ Bb,
    int m0, int nrow0, int k0, int tid, u16* As, u16* Bs)
{
#pragma unroll
    for (int it = 0; it < 4; it++) {
        int c = it * 512 + tid;            // 2048 chunks of 16B
        int k2 = c >> 8, row = c & 255;
        int acol = k0 + k2 * 8;
        if (acol >= KPA) acol -= KPA;
        __builtin_amdgcn_global_load_lds(Ab + (size_t)(m0 + row) * KPA + acol,
                                         As + (size_t)c * 8, 16, 0, 0);
    }
#pragma unroll
    for (int it = 0; it < 4; it++) {
        int c = it * 512 + tid;
        int k2 = c >> 8, row = c & 255;
        __builtin_amdgcn_global_load_lds(Bb + (size_t)(nrow0 + row) * KP + k0 + k2 * 8,
                                         Bs + (size_t)c * 8, 16, 0, 0);
    }
}

__global__ __launch_bounds__(512) void qkv_mfma(
    const u16* __restrict__ Ah, const u16* __restrict__ BTall,
    const float* __restrict__ bq, const float* __restrict__ bk, const float* __restrict__ bv,
    __bf16* __restrict__ qo, __bf16* __restrict__ ko, __bf16* __restrict__ vo)
{
    const int wg  = blockIdx.x;                  // 0..191
    const int xcd = wg & 7, idx = wg >> 3;       // 24 tiles per XCD
    const int by  = xcd * 2 + idx / 12;          // 0..15  (A-band reuse in XCD L2)
    const int bx  = idx % 12;                    // 0..11

    __shared__ __attribute__((aligned(16))) u16 As[2][16384], Bs[2][16384];

    const int tid  = threadIdx.x;
    const int lane = tid & 63;
    const int wave = tid >> 6;                   // 0..7
    const int wr   = wave >> 2, wc = wave & 3;   // 2M x 4N
    const int rl   = lane & 15, lq = lane >> 4;  // frag row / k-octet select

    const int m0    = by * 256;
    const int nrow0 = bx * 256;

    f32x4 acc[8][4] = {};

    stage256(Ah, BTall, m0, nrow0, 0, tid, As[0], Bs[0]);
    __syncthreads();

    int cur = 0;
    for (int k0 = 0; k0 < KP; k0 += 64) {
        const u16* Ac = As[cur];
        const u16* Bc = Bs[cur];
        if (k0 + 64 < KP)
            stage256(Ah, BTall, m0, nrow0, k0 + 64, tid, As[cur ^ 1], Bs[cur ^ 1]);

#pragma unroll
        for (int kk = 0; kk < 2; kk++) {
            bf16x8 af[8], bfr[4];
#pragma unroll
            for (int mi = 0; mi < 8; mi++)
                af[mi] = *(const bf16x8*)(Ac +
                    (size_t)((kk * 4 + lq) * 256 + wr * 128 + mi * 16 + rl) * 8);
#pragma unroll
            for (int ni = 0; ni < 4; ni++)
                bfr[ni] = *(const bf16x8*)(Bc +
                    (size_t)((kk * 4 + lq) * 256 + wc * 64 + ni * 16 + rl) * 8);
#pragma unroll
            for (int mi = 0; mi < 8; mi++)
#pragma unroll
                for (int ni = 0; ni < 4; ni++)
                    acc[mi][ni] = MFMA16(af[mi], bfr[ni], acc[mi][ni]);
        }
        __syncthreads();
        cur ^= 1;
    }

    // epilogue: z constant per block (256-aligned within each 1024 n-range)
    const int z   = bx >> 2;                     // 0:q 1:k 2:v
    const int n0l = (bx & 3) * 256;
    const float* bias = (z == 0) ? bq : (z == 1) ? bk : bv;
    __bf16* O         = (z == 0) ? qo : (z == 1) ? ko : vo;
    const float qs    = (z == 0) ? SCALING : 1.0f;

#pragma unroll
    for (int mi = 0; mi < 8; mi++) {
#pragma unroll
        for (int ni = 0; ni < 4; ni++) {
            int n = n0l + wc * 64 + ni * 16 + rl;
            int h = n >> 6, d = n & 63;
            float bb = bias[n];
#pragma unroll
            for (int r = 0; r < 4; r++) {
                int m = m0 + wr * 128 + mi * 16 + lq * 4 + r;
                int b = m >> 10, t = m & 1023;
                float v = (acc[mi][ni][r] + bb) * qs;
                O[(size_t)((b * NH + h) * LQ + t) * HD + d] = (__bf16)v;
            }
        }
    }
}

// ---------------------------------------------------------------------------
// Output projection: 128x128 tile, BK=32, 8 waves (2M x 4N, wave 64x32),
// 2-phase dbuf. Grid 256 = 1 block/CU -> 8 waves/CU for latency hiding.
// ---------------------------------------------------------------------------
__device__ __forceinline__ void stage128(
    const u16* __restrict__ Ab, const u16* __restrict__ Bb,
    int m0, int nrow0, int k0, int tid, u16* As, u16* Bs)
{
    {
        int c = tid;                       // 512 chunks of 16B
        int k2 = c >> 7, row = c & 127;
        int acol = k0 + k2 * 8;
        if (acol >= KPA) acol -= KPA;
        __builtin_amdgcn_global_load_lds(Ab + (size_t)(m0 + row) * KPA + acol,
                                         As + (size_t)c * 8, 16, 0, 0);
    }
    {
        int c = tid;
        int k2 = c >> 7, row = c & 127;
        __builtin_amdgcn_global_load_lds(Bb + (size_t)(nrow0 + row) * KP + k0 + k2 * 8,
                                         Bs + (size_t)c * 8, 16, 0, 0);
    }
}

__global__ __launch_bounds__(512) void oproj_mfma(
    const u16* __restrict__ Ao, const u16* __restrict__ BTo,
    const float* __restrict__ bo, float* __restrict__ O)
{
    const int wg  = blockIdx.x;                  // 0..255
    const int xcd = wg & 7, idx = wg >> 3;       // 32 tiles per XCD
    const int swz = xcd * 32 + idx;
    const int by  = swz >> 3, bx = swz & 7;      // 4 m-bands x 8 n per XCD

    __shared__ __attribute__((aligned(16))) u16 As[2][4096], Bs[2][4096];

    const int tid  = threadIdx.x;
    const int lane = tid & 63;
    const int wave = tid >> 6;
    const int wr   = wave >> 2, wc = wave & 3;   // 2M x 4N, wave tile 64x32
    const int rl   = lane & 15, lq = lane >> 4;

    const int m0 = by * 128, n0 = bx * 128;

    f32x4 acc[4][2] = {};

    stage128(Ao, BTo, m0, n0, 0, tid, As[0], Bs[0]);
    __syncthreads();

    int cur = 0;
    for (int k0 = 0; k0 < KP; k0 += 32) {
        const u16* Ac = As[cur];
        const u16* Bc = Bs[cur];
        if (k0 + 32 < KP)
            stage128(Ao, BTo, m0, n0, k0 + 32, tid, As[cur ^ 1], Bs[cur ^ 1]);

        bf16x8 af[4], bfr[2];
#pragma unroll
        for (int mi = 0; mi < 4; mi++)
            af[mi] = *(const bf16x8*)(Ac + (size_t)(lq * 128 + wr * 64 + mi * 16 + rl) * 8);
#pragma unroll
        for (int ni = 0; ni < 2; ni++)
            bfr[ni] = *(const bf16x8*)(Bc + (size_t)(lq * 128 + wc * 32 + ni * 16 + rl) * 8);
#pragma unroll
        for (int mi = 0; mi < 4; mi++)
#pragma unroll
            for (int ni = 0; ni < 2; ni++)
                acc[mi][ni] = MFMA16(af[mi], bfr[ni], acc[mi][ni]);

        __syncthreads();
        cur ^= 1;
    }

#pragma unroll
    for (int mi = 0; mi < 4; mi++)
#pragma unroll
        for (int ni = 0; ni < 2; ni++) {
            int n = n0 + wc * 32 + ni * 16 + rl;
            float bb = bo[n];
#pragma unroll
            for (int r = 0; r < 4; r++) {
                int m = m0 + wr * 64 + mi * 16 + lq * 4 + r;
                O[(size_t)m * EE + n] = acc[mi][ni][r] + bb;
            }
        }
}

// ---------------------------------------------------------------------------
// V transpose: vb[bh][s][d] bf16 -> vtb[bh][d][s] bf16 (per 64-s tile)
// ---------------------------------------------------------------------------
__global__ __launch_bounds__(256) void vtrans(
    const __bf16* __restrict__ vb, __bf16* __restrict__ vtb)
{
    const int bh = blockIdx.y;
    const int s0 = blockIdx.x * 64;
    const int tid = threadIdx.x;
    __shared__ float t[64][65];

#pragma unroll
    for (int rr = 0; rr < 2; rr++) {
        int f = rr * 256 + tid;
        int s = f >> 3, c8 = f & 7;
        bf16x8 v = *(const bf16x8*)(vb + ((size_t)bh * LQ + s0 + s) * HD + c8 * 8);
#pragma unroll
        for (int j = 0; j < 8; j++) t[c8 * 8 + j][s] = (float)v[j];
    }
    __syncthreads();
#pragma unroll
    for (int rr = 0; rr < 2; rr++) {
        int f = rr * 256 + tid;
        int d = f >> 3, c8 = f & 7;
        bf16x8 o;
#pragma unroll
        for (int j = 0; j < 8; j++) o[j] = (__bf16)t[d][c8 * 8 + j];
        *(bf16x8*)(vtb + ((size_t)bh * HD + d) * LQ + s0 + c8 * 8) = o;
    }
}

// ---------------------------------------------------------------------------
// MFMA flash attention with windowed relative-position terms.
// Epilogue writes hi|lo split bf16 rows (stride KPA) for the o-proj GEMM.
// ---------------------------------------------------------------------------
__device__ __forceinline__ bf16x8 ld_frag(const u16* base, int row, int col)
{
    int off = (row * 128 + col * 2) ^ ((row & 7) << 4);
    return *(const bf16x8*)((const char*)base + off);
}

__global__ __launch_bounds__(256) void attn_mfma(
    const u16* __restrict__ qb, const u16* __restrict__ kb,
    const u16* __restrict__ vtb,
    const float* __restrict__ relk, const float* __restrict__ relv,
    __bf16* __restrict__ Ao)
{
    __shared__ __attribute__((aligned(16))) u16 q_lds[64 * 64];
    __shared__ __attribute__((aligned(16))) u16 k_lds[64 * 64];
    __shared__ __attribute__((aligned(16))) u16 v_lds[64 * 64];
    __shared__ __attribute__((aligned(16))) u16 p_lds[64 * 64];  // wave-private 16x64 regions
    __shared__ float R_lds[64 * 9];
    __shared__ float rk_lds[9 * 64];
    __shared__ float rv_lds[9 * 64];

    const int tid  = threadIdx.x;
    const int lane = tid & 63;
    const int wave = tid >> 6;
    const int bh   = blockIdx.y;
    const int q0   = blockIdx.x * 64;

    // ---- stage Q block (64x64 bf16) with inverse-swizzled source ----
#pragma unroll
    for (int rr = 0; rr < 2; rr++) {
        int f = rr * 256 + tid;
        int row = f >> 3, c8 = f & 7;
        const u16* src = qb + ((size_t)bh * LQ + q0 + row) * HD + ((c8 ^ (row & 7)) * 8);
        __builtin_amdgcn_global_load_lds(src, q_lds + (size_t)(f & ~63) * 8, 16, 0, 0);
    }
    for (int u = tid; u < 144; u += 256)
        *(float4*)&rk_lds[u * 4] = *(const float4*)&relk[u * 4];
    for (int u = tid; u < 144; u += 256)
        *(float4*)&rv_lds[u * 4] = *(const float4*)&relv[u * 4];
    __syncthreads();

    // ---- R[t][i] = q[t] . relk[i]  (64 x 9) ----
    for (int j = tid; j < 576; j += 256) {
        int tl = j / 9, i = j - tl * 9;
        float acc = 0.f;
        for (int d = 0; d < 64; d++) {
            int off = (tl * 128 + d * 2) ^ ((tl & 7) << 4);
            float qv = (float)*(const __bf16*)((const char*)q_lds + off);
            acc += qv * rk_lds[i * 64 + d];
        }
        R_lds[tl * 9 + i] = acc;
    }

    bf16x8 qa[2];
    qa[0] = ld_frag(q_lds, wave * 16 + (lane & 15), (lane >> 4) * 8);
    qa[1] = ld_frag(q_lds, wave * 16 + (lane & 15), 32 + (lane >> 4) * 8);

    __syncthreads();

    f32x4 of[4] = {};
    float m_r[4], l_r[4];
#pragma unroll
    for (int r = 0; r < 4; r++) { m_r[r] = -1e30f; l_r[r] = 0.f; }

    const u16* pw = p_lds + wave * 1024;
    u16* pww      = p_lds + wave * 1024;

    for (int s0 = 0; s0 < LQ; s0 += 64) {
#pragma unroll
        for (int rr = 0; rr < 2; rr++) {
            int f = rr * 256 + tid;
            int row = f >> 3, c8 = f & 7;
            const u16* srck = kb + ((size_t)bh * LQ + s0 + row) * HD + ((c8 ^ (row & 7)) * 8);
            __builtin_amdgcn_global_load_lds(srck, k_lds + (size_t)(f & ~63) * 8, 16, 0, 0);
            const u16* srcv = vtb + ((size_t)bh * HD + row) * LQ + s0 + ((c8 ^ (row & 7)) * 8);
            __builtin_amdgcn_global_load_lds(srcv, v_lds + (size_t)(f & ~63) * 8, 16, 0, 0);
        }
        __syncthreads();

        // ---- S = Q @ K^T ----
        f32x4 sf[4] = {};
#pragma unroll
        for (int sub = 0; sub < 4; sub++) {
#pragma unroll
            for (int kk = 0; kk < 2; kk++) {
                bf16x8 kf = ld_frag(k_lds, sub * 16 + (lane & 15), kk * 32 + (lane >> 4) * 8);
                sf[sub] = MFMA16(qa[kk], kf, sf[sub]);
            }
        }

        int drel = s0 - q0;
        bool diag = (drel == -64) || (drel == 0) || (drel == 64);
        if (diag) {
#pragma unroll
            for (int sub = 0; sub < 4; sub++) {
#pragma unroll
                for (int r = 0; r < 4; r++) {
                    int tl = wave * 16 + (lane >> 4) * 4 + r;
                    int s  = s0 + sub * 16 + (lane & 15);
                    int i  = s - (q0 + tl) + 4;
                    if ((unsigned)i <= 8u) sf[sub][r] += R_lds[tl * 9 + i];
                }
            }
        }

        // ---- online softmax ----
        float tmax[4];
#pragma unroll
        for (int r = 0; r < 4; r++) {
            float m0 = fmaxf(fmaxf(sf[0][r], sf[1][r]), fmaxf(sf[2][r], sf[3][r]));
#pragma unroll
            for (int msk = 8; msk >= 1; msk >>= 1) m0 = fmaxf(m0, __shfl_xor(m0, msk, 64));
            tmax[r] = m0;
        }
#pragma unroll
        for (int r = 0; r < 4; r++) {
            float mn = fmaxf(m_r[r], tmax[r]);
            float sc = __expf(m_r[r] - mn);
            m_r[r] = mn;
            l_r[r] *= sc;
#pragma unroll
            for (int sub = 0; sub < 4; sub++) of[sub][r] *= sc;
        }
#pragma unroll
        for (int sub = 0; sub < 4; sub++) {
#pragma unroll
            for (int r = 0; r < 4; r++) {
                float p = __expf(sf[sub][r] - m_r[r]);
                l_r[r] += p;
                int q = (lane >> 4) * 4 + r;
                int off = (q * 128 + (sub * 16 + (lane & 15)) * 2) ^ ((q & 7) << 4);
                *(__bf16*)((char*)pww + off) = (__bf16)p;
            }
        }

        // ---- O += P @ V ----
#pragma unroll
        for (int kk = 0; kk < 2; kk++) {
            bf16x8 pa = ld_frag(pw, lane & 15, kk * 32 + (lane >> 4) * 8);
#pragma unroll
            for (int dsub = 0; dsub < 4; dsub++) {
                bf16x8 vf = ld_frag(v_lds, dsub * 16 + (lane & 15), kk * 32 + (lane >> 4) * 8);
                of[dsub] = MFMA16(pa, vf, of[dsub]);
            }
        }

        if (diag) {
#pragma unroll
            for (int r = 0; r < 4; r++) {
                int q  = (lane >> 4) * 4 + r;
                int tl = wave * 16 + q;
#pragma unroll
                for (int i = 0; i < 9; i++) {
                    int s  = q0 + tl + i - 4;
                    int sl = s - s0;
                    if ((unsigned)sl < 64u) {
                        int off = (q * 128 + sl * 2) ^ ((q & 7) << 4);
                        float p = (float)*(const __bf16*)((const char*)pww + off);
#pragma unroll
                        for (int dsub = 0; dsub < 4; dsub++)
                            of[dsub][r] += p * rv_lds[i * 64 + dsub * 16 + (lane & 15)];
                    }
                }
            }
        }
        __syncthreads();
    }

    // ---- final normalize + write hi|lo split rows (stride KPA) ----
#pragma unroll
    for (int r = 0; r < 4; r++) {
        float s = l_r[r];
#pragma unroll
        for (int msk = 8; msk >= 1; msk >>= 1) s += __shfl_xor(s, msk, 64);
        l_r[r] = 1.0f / s;
    }
    const int b = bh >> 4, h = bh & 15;
#pragma unroll
    for (int dsub = 0; dsub < 4; dsub++) {
#pragma unroll
        for (int r = 0; r < 4; r++) {
            int t = q0 + wave * 16 + (lane >> 4) * 4 + r;
            int e = h * 64 + dsub * 16 + (lane & 15);
            float v = of[dsub][r] * l_r[r];
            __bf16 hh, ll; split_bf16(v, hh, ll);
            __bf16* row = Ao + (size_t)(b * LQ + t) * KPA;
            row[e]        = hh;
            row[1024 + e] = ll;
        }
    }
}

// ---------------------------------------------------------------------------
extern "C" void kernel_launch(void* const* d_in, const int* in_sizes, int n_in,
                              void* d_out, int out_size, void* d_ws, size_t ws_size,
                              hipStream_t stream)
{
    const float* hidden = (const float*)d_in[0];
    const float* Wq = (const float*)d_in[1];
    const float* bq = (const float*)d_in[2];
    const float* Wk = (const float*)d_in[3];
    const float* bk = (const float*)d_in[4];
    const float* Wv = (const float*)d_in[5];
    const float* bv = (const float*)d_in[6];
    const float* Wo = (const float*)d_in[7];
    const float* bo = (const float*)d_in[8];
    const float* relk = (const float*)d_in[9];
    const float* relv = (const float*)d_in[10];

    char* w = (char*)d_ws;
    // Workspace layout: Ah/Ao 16 MB at 0; BTq at 16M, BTk at 22M, BTv at 28M
    // (contiguous N=3072 for the fused QKV GEMM); BTo at 34M; qbw 40M, kbw 48M,
    // vbw 56M, vtbw 64M; 72 MB total.
    __bf16* Ah   = (__bf16*)(w);
    __bf16* Ao   = (__bf16*)(w);
    __bf16* BTq  = (__bf16*)(w + (16u << 20));
    __bf16* BTk  = (__bf16*)(w + (22u << 20));
    __bf16* BTv  = (__bf16*)(w + (28u << 20));
    __bf16* BTo  = (__bf16*)(w + (34u << 20));
    __bf16* qbw  = (__bf16*)(w + (40u << 20));
    __bf16* kbw  = (__bf16*)(w + (48u << 20));
    __bf16* vbw  = (__bf16*)(w + (56u << 20));
    __bf16* vtbw = (__bf16*)(w + (64u << 20));
    float*  out  = (float*)d_out;

    conv_hidden<<<1024, 256, 0, stream>>>(hidden, Ah);
    conv_w<<<dim3(16, 16, 4), 256, 0, stream>>>(Wq, Wk, Wv, Wo, BTq, BTk, BTv, BTo);
    qkv_mfma<<<192, 512, 0, stream>>>((const u16*)Ah, (const u16*)BTq,
                                      bq, bk, bv, qbw, kbw, vbw);
    vtrans<<<dim3(16, 64), 256, 0, stream>>>(vbw, vtbw);
    attn_mfma<<<dim3(16, 64), 256, 0, stream>>>((const u16*)qbw, (const u16*)kbw,
        (const u16*)vtbw, relk, relv, Ao);
    oproj_mfma<<<256, 512, 0, stream>>>((const u16*)Ao, (const u16*)BTo, bo, out);
}

// Round 7
// 303.226 us; speedup vs baseline: 5.2859x; 1.1559x over previous
//
#include <hip/hip_runtime.h>
#include <math.h>

#define LQ 1024      // sequence length
#define EE 1024      // embed dim
#define NH 16        // heads
#define HD 64        // head dim
#define KP 3072      // split-GEMM K' (hi*hi | lo*hi | hi*lo)
#define KPA 2048     // A storage cols (hi | lo); third block reuses hi
#define SCALING 0.125f

typedef unsigned short u16;
typedef __bf16 bf16x8 __attribute__((ext_vector_type(8)));
typedef __bf16 bf16x4 __attribute__((ext_vector_type(4)));
typedef float f32x4 __attribute__((ext_vector_type(4)));

#define MFMA16(a, b, c) __builtin_amdgcn_mfma_f32_16x16x32_bf16(a, b, c, 0, 0, 0)

__device__ __forceinline__ void split_bf16(float x, __bf16& h, __bf16& l)
{
    h = (__bf16)x;
    l = (__bf16)(x - (float)h);
}

// ---------------------------------------------------------------------------
// hidden (4096x1024 fp32) -> Ah (4096 x 2048 bf16): [hi | lo]
// ---------------------------------------------------------------------------
__global__ __launch_bounds__(256) void conv_hidden(
    const float* __restrict__ A, __bf16* __restrict__ Ah)
{
    int t = blockIdx.x * 256 + threadIdx.x;
#pragma unroll
    for (int it = 0; it < 4; it++) {
        int f = t + it * 262144;            // float4 index, total 1048576
        int m = f >> 8, c4 = f & 255;
        float4 x = ((const float4*)A)[f];
        float xs[4] = {x.x, x.y, x.z, x.w};
        bf16x4 hv, lv;
#pragma unroll
        for (int j = 0; j < 4; j++) {
            __bf16 h, l; split_bf16(xs[j], h, l);
            hv[j] = h; lv[j] = l;
        }
        __bf16* row = Ah + (size_t)m * KPA;
        *(bf16x4*)(row + c4 * 4)        = hv;
        *(bf16x4*)(row + 1024 + c4 * 4) = lv;
    }
}

// ---------------------------------------------------------------------------
// W (1024x1024 fp32, [k][n]) -> BT (1024 x 3072 bf16, [n][hiT | hiT | loT])
// ---------------------------------------------------------------------------
__global__ __launch_bounds__(256) void conv_w(
    const float* __restrict__ Wq, const float* __restrict__ Wk,
    const float* __restrict__ Wv, const float* __restrict__ Wo,
    __bf16* __restrict__ BTq, __bf16* __restrict__ BTk,
    __bf16* __restrict__ BTv, __bf16* __restrict__ BTo)
{
    const int z = blockIdx.z;
    const float* W = (z == 0) ? Wq : (z == 1) ? Wk : (z == 2) ? Wv : Wo;
    __bf16* BT     = (z == 0) ? BTq : (z == 1) ? BTk : (z == 2) ? BTv : BTo;
    const int n0 = blockIdx.x * 64, k0 = blockIdx.y * 64;
    const int tid = threadIdx.x;
    __shared__ float tbuf[64][65];

#pragma unroll
    for (int rr = 0; rr < 4; rr++) {
        int f = rr * 256 + tid;            // 1024 float4 loads
        int kl = f >> 4, n4 = f & 15;
        float4 x = *(const float4*)&W[(size_t)(k0 + kl) * EE + n0 + n4 * 4];
        tbuf[kl][n4 * 4 + 0] = x.x;
        tbuf[kl][n4 * 4 + 1] = x.y;
        tbuf[kl][n4 * 4 + 2] = x.z;
        tbuf[kl][n4 * 4 + 3] = x.w;
    }
    __syncthreads();
#pragma unroll
    for (int rr = 0; rr < 2; rr++) {
        int f = rr * 256 + tid;            // 512 chunks of 8 along k
        int nl = f >> 3, c8 = f & 7;
        bf16x8 hv, lv;
#pragma unroll
        for (int j = 0; j < 8; j++) {
            __bf16 h, l; split_bf16(tbuf[c8 * 8 + j][nl], h, l);
            hv[j] = h; lv[j] = l;
        }
        __bf16* row = BT + (size_t)(n0 + nl) * KP + k0;
        *(bf16x8*)(row + c8 * 8)        = hv;
        *(bf16x8*)(row + 1024 + c8 * 8) = hv;
        *(bf16x8*)(row + 2048 + c8 * 8) = lv;
    }
}

// ---------------------------------------------------------------------------
// Fused QKV projection: 256x192 tile, BK=64, 8 waves, counted-vmcnt pipeline.
// Grid 256 = 16 by x 16 bx -> every CU busy. XCD swizzle: 2 m-bands per XCD.
// LDS/buf: A [k2][row256][8] 32KB + B [k2][row192][8] 24KB; 2 bufs = 112KB.
// Pipeline: stage(k0),stage(k1); loop { vmcnt(7); bar; compute(cur);
//   lgkmcnt(0); bar; stage(cur,k+2); flip; }  -- loads span barriers (T4).
// ---------------------------------------------------------------------------
__device__ __forceinline__ void stage_qkv(
    const u16* __restrict__ Ab, const u16* __restrict__ Bb,
    int m0, int nrow0, int k0, int tid, u16* As, u16* Bs)
{
#pragma unroll
    for (int it = 0; it < 4; it++) {
        int c = it * 512 + tid;            // 0..2047: A chunks (k2 0..7, row 0..255)
        int k2 = c >> 8, row = c & 255;
        int acol = k0 + k2 * 8;
        if (acol >= KPA) acol -= KPA;      // third hi-block reuses cols 0:1024
        __builtin_amdgcn_global_load_lds(Ab + (size_t)(m0 + row) * KPA + acol,
                                         As + (size_t)c * 8, 16, 0, 0);
    }
#pragma unroll
    for (int it = 0; it < 3; it++) {
        int c = it * 512 + tid;            // 0..1535: B chunks (k2 0..7, row 0..191)
        int k2 = c / 192, row = c - k2 * 192;
        __builtin_amdgcn_global_load_lds(Bb + (size_t)(nrow0 + row) * KP + k0 + k2 * 8,
                                         Bs + (size_t)c * 8, 16, 0, 0);
    }
}

__global__ __launch_bounds__(512) void qkv_mfma(
    const u16* __restrict__ Ah, const u16* __restrict__ BTall,
    const float* __restrict__ bq, const float* __restrict__ bk, const float* __restrict__ bv,
    __bf16* __restrict__ qo, __bf16* __restrict__ ko, __bf16* __restrict__ vo)
{
    const int wg  = blockIdx.x;                  // 0..255
    const int xcd = wg & 7, idx = wg >> 3;       // 32 tiles per XCD
    const int tile = xcd * 32 + idx;
    const int by  = tile >> 4;                   // 0..15 (2 consecutive per XCD)
    const int bx  = tile & 15;                   // 0..15

    __shared__ __attribute__((aligned(16))) u16 As[2][16384];
    __shared__ __attribute__((aligned(16))) u16 Bs[2][12288];

    const int tid  = threadIdx.x;
    const int lane = tid & 63;
    const int wave = tid >> 6;                   // 0..7
    const int wr   = wave >> 2, wc = wave & 3;   // 2M x 4N (wave tile 128x48)
    const int rl   = lane & 15, lq = lane >> 4;

    const int m0    = by * 256;
    const int nrow0 = bx * 192;                  // row into concatenated BT (0..3071)

    f32x4 acc[8][3] = {};

    auto compute = [&](const u16* Ac, const u16* Bc) {
#pragma unroll
        for (int kk = 0; kk < 2; kk++) {
            bf16x8 af[8], bfr[3];
#pragma unroll
            for (int mi = 0; mi < 8; mi++)
                af[mi] = *(const bf16x8*)(Ac +
                    (size_t)((kk * 4 + lq) * 256 + wr * 128 + mi * 16 + rl) * 8);
#pragma unroll
            for (int ni = 0; ni < 3; ni++)
                bfr[ni] = *(const bf16x8*)(Bc +
                    (size_t)((kk * 4 + lq) * 192 + wc * 48 + ni * 16 + rl) * 8);
#pragma unroll
            for (int mi = 0; mi < 8; mi++)
#pragma unroll
                for (int ni = 0; ni < 3; ni++)
                    acc[mi][ni] = MFMA16(af[mi], bfr[ni], acc[mi][ni]);
        }
    };

    stage_qkv(Ah, BTall, m0, nrow0, 0,  tid, As[0], Bs[0]);
    stage_qkv(Ah, BTall, m0, nrow0, 64, tid, As[1], Bs[1]);

    int cur = 0;
    for (int i = 0; i < 47; i++) {               // NK = 3072/64 = 48, last peeled
        asm volatile("s_waitcnt vmcnt(7)" ::: "memory");   // cur's 7 loads done
        __builtin_amdgcn_s_barrier();
        compute(As[cur], Bs[cur]);
        asm volatile("s_waitcnt lgkmcnt(0)" ::: "memory"); // ds_reads of cur done
        __builtin_amdgcn_s_barrier();
        if (i + 2 < 48)
            stage_qkv(Ah, BTall, m0, nrow0, (i + 2) * 64, tid, As[cur], Bs[cur]);
        cur ^= 1;
    }
    asm volatile("s_waitcnt vmcnt(0)" ::: "memory");
    __builtin_amdgcn_s_barrier();
    compute(As[cur], Bs[cur]);

    // epilogue: z may vary across the 192-wide tile; resolve per column
#pragma unroll
    for (int ni = 0; ni < 3; ni++) {
        int ng = nrow0 + wc * 48 + ni * 16 + rl;  // concat n (0..3071)
        int z  = ng >> 10, nl = ng & 1023;
        int h  = nl >> 6, d = nl & 63;
        const float* bias = (z == 0) ? bq : (z == 1) ? bk : bv;
        __bf16* O         = (z == 0) ? qo : (z == 1) ? ko : vo;
        const float qs    = (z == 0) ? SCALING : 1.0f;
        float bb = bias[nl];
#pragma unroll
        for (int mi = 0; mi < 8; mi++) {
#pragma unroll
            for (int r = 0; r < 4; r++) {
                int m = m0 + wr * 128 + mi * 16 + lq * 4 + r;
                int b = m >> 10, t = m & 1023;
                float v = (acc[mi][ni][r] + bb) * qs;
                O[(size_t)((b * NH + h) * LQ + t) * HD + d] = (__bf16)v;
            }
        }
    }
}

// ---------------------------------------------------------------------------
// Output projection: 128x128 tile, BK=64, 8 waves (2M x 4N, wave 64x32),
// counted-vmcnt pipeline (4 loads/thread/stage). Grid 256 = 1 block/CU.
// ---------------------------------------------------------------------------
__device__ __forceinline__ void stage_op(
    const u16* __restrict__ Ab, const u16* __restrict__ Bb,
    int m0, int nrow0, int k0, int tid, u16* As, u16* Bs)
{
#pragma unroll
    for (int it = 0; it < 2; it++) {
        int c = it * 512 + tid;            // 0..1023 (k2 0..7, row 0..127)
        int k2 = c >> 7, row = c & 127;
        int acol = k0 + k2 * 8;
        if (acol >= KPA) acol -= KPA;
        __builtin_amdgcn_global_load_lds(Ab + (size_t)(m0 + row) * KPA + acol,
                                         As + (size_t)c * 8, 16, 0, 0);
    }
#pragma unroll
    for (int it = 0; it < 2; it++) {
        int c = it * 512 + tid;
        int k2 = c >> 7, row = c & 127;
        __builtin_amdgcn_global_load_lds(Bb + (size_t)(nrow0 + row) * KP + k0 + k2 * 8,
                                         Bs + (size_t)c * 8, 16, 0, 0);
    }
}

__global__ __launch_bounds__(512) void oproj_mfma(
    const u16* __restrict__ Ao, const u16* __restrict__ BTo,
    const float* __restrict__ bo, float* __restrict__ O)
{
    const int wg  = blockIdx.x;                  // 0..255
    const int xcd = wg & 7, idx = wg >> 3;
    const int swz = xcd * 32 + idx;
    const int by  = swz >> 3, bx = swz & 7;      // 4 m-bands x 8 n per XCD

    __shared__ __attribute__((aligned(16))) u16 As[2][8192], Bs[2][8192];

    const int tid  = threadIdx.x;
    const int lane = tid & 63;
    const int wave = tid >> 6;
    const int wr   = wave >> 2, wc = wave & 3;   // wave tile 64x32
    const int rl   = lane & 15, lq = lane >> 4;

    const int m0 = by * 128, n0 = bx * 128;

    f32x4 acc[4][2] = {};

    auto compute = [&](const u16* Ac, const u16* Bc) {
#pragma unroll
        for (int kk = 0; kk < 2; kk++) {
            bf16x8 af[4], bfr[2];
#pragma unroll
            for (int mi = 0; mi < 4; mi++)
                af[mi] = *(const bf16x8*)(Ac +
                    (size_t)((kk * 4 + lq) * 128 + wr * 64 + mi * 16 + rl) * 8);
#pragma unroll
            for (int ni = 0; ni < 2; ni++)
                bfr[ni] = *(const bf16x8*)(Bc +
                    (size_t)((kk * 4 + lq) * 128 + wc * 32 + ni * 16 + rl) * 8);
#pragma unroll
            for (int mi = 0; mi < 4; mi++)
#pragma unroll
                for (int ni = 0; ni < 2; ni++)
                    acc[mi][ni] = MFMA16(af[mi], bfr[ni], acc[mi][ni]);
        }
    };

    stage_op(Ao, BTo, m0, n0, 0,  tid, As[0], Bs[0]);
    stage_op(Ao, BTo, m0, n0, 64, tid, As[1], Bs[1]);

    int cur = 0;
    for (int i = 0; i < 47; i++) {
        asm volatile("s_waitcnt vmcnt(4)" ::: "memory");
        __builtin_amdgcn_s_barrier();
        compute(As[cur], Bs[cur]);
        asm volatile("s_waitcnt lgkmcnt(0)" ::: "memory");
        __builtin_amdgcn_s_barrier();
        if (i + 2 < 48)
            stage_op(Ao, BTo, m0, n0, (i + 2) * 64, tid, As[cur], Bs[cur]);
        cur ^= 1;
    }
    asm volatile("s_waitcnt vmcnt(0)" ::: "memory");
    __builtin_amdgcn_s_barrier();
    compute(As[cur], Bs[cur]);

#pragma unroll
    for (int mi = 0; mi < 4; mi++)
#pragma unroll
        for (int ni = 0; ni < 2; ni++) {
            int n = n0 + wc * 32 + ni * 16 + rl;
            float bb = bo[n];
#pragma unroll
            for (int r = 0; r < 4; r++) {
                int m = m0 + wr * 64 + mi * 16 + lq * 4 + r;
                O[(size_t)m * EE + n] = acc[mi][ni][r] + bb;
            }
        }
}

// ---------------------------------------------------------------------------
// V transpose: vb[bh][s][d] bf16 -> vtb[bh][d][s] bf16 (per 64-s tile)
// ---------------------------------------------------------------------------
__global__ __launch_bounds__(256) void vtrans(
    const __bf16* __restrict__ vb, __bf16* __restrict__ vtb)
{
    const int bh = blockIdx.y;
    const int s0 = blockIdx.x * 64;
    const int tid = threadIdx.x;
    __shared__ float t[64][65];

#pragma unroll
    for (int rr = 0; rr < 2; rr++) {
        int f = rr * 256 + tid;
        int s = f >> 3, c8 = f & 7;
        bf16x8 v = *(const bf16x8*)(vb + ((size_t)bh * LQ + s0 + s) * HD + c8 * 8);
#pragma unroll
        for (int j = 0; j < 8; j++) t[c8 * 8 + j][s] = (float)v[j];
    }
    __syncthreads();
#pragma unroll
    for (int rr = 0; rr < 2; rr++) {
        int f = rr * 256 + tid;
        int d = f >> 3, c8 = f & 7;
        bf16x8 o;
#pragma unroll
        for (int j = 0; j < 8; j++) o[j] = (__bf16)t[d][c8 * 8 + j];
        *(bf16x8*)(vtb + ((size_t)bh * HD + d) * LQ + s0 + c8 * 8) = o;
    }
}

// ---------------------------------------------------------------------------
// MFMA flash attention with windowed relative-position terms.
// Epilogue writes hi|lo split bf16 rows (stride KPA) for the o-proj GEMM.
// ---------------------------------------------------------------------------
__device__ __forceinline__ bf16x8 ld_frag(const u16* base, int row, int col)
{
    int off = (row * 128 + col * 2) ^ ((row & 7) << 4);
    return *(const bf16x8*)((const char*)base + off);
}

__global__ __launch_bounds__(256) void attn_mfma(
    const u16* __restrict__ qb, const u16* __restrict__ kb,
    const u16* __restrict__ vtb,
    const float* __restrict__ relk, const float* __restrict__ relv,
    __bf16* __restrict__ Ao)
{
    __shared__ __attribute__((aligned(16))) u16 q_lds[64 * 64];
    __shared__ __attribute__((aligned(16))) u16 k_lds[64 * 64];
    __shared__ __attribute__((aligned(16))) u16 v_lds[64 * 64];
    __shared__ __attribute__((aligned(16))) u16 p_lds[64 * 64];  // wave-private 16x64 regions
    __shared__ float R_lds[64 * 9];
    __shared__ float rk_lds[9 * 64];
    __shared__ float rv_lds[9 * 64];

    const int tid  = threadIdx.x;
    const int lane = tid & 63;
    const int wave = tid >> 6;
    const int bh   = blockIdx.y;
    const int q0   = blockIdx.x * 64;

    // ---- stage Q block (64x64 bf16) with inverse-swizzled source ----
#pragma unroll
    for (int rr = 0; rr < 2; rr++) {
        int f = rr * 256 + tid;
        int row = f >> 3, c8 = f & 7;
        const u16* src = qb + ((size_t)bh * LQ + q0 + row) * HD + ((c8 ^ (row & 7)) * 8);
        __builtin_amdgcn_global_load_lds(src, q_lds + (size_t)(f & ~63) * 8, 16, 0, 0);
    }
    for (int u = tid; u < 144; u += 256)
        *(float4*)&rk_lds[u * 4] = *(const float4*)&relk[u * 4];
    for (int u = tid; u < 144; u += 256)
        *(float4*)&rv_lds[u * 4] = *(const float4*)&relv[u * 4];
    __syncthreads();

    // ---- R[t][i] = q[t] . relk[i]  (64 x 9) ----
    for (int j = tid; j < 576; j += 256) {
        int tl = j / 9, i = j - tl * 9;
        float acc = 0.f;
        for (int d = 0; d < 64; d++) {
            int off = (tl * 128 + d * 2) ^ ((tl & 7) << 4);
            float qv = (float)*(const __bf16*)((const char*)q_lds + off);
            acc += qv * rk_lds[i * 64 + d];
        }
        R_lds[tl * 9 + i] = acc;
    }

    bf16x8 qa[2];
    qa[0] = ld_frag(q_lds, wave * 16 + (lane & 15), (lane >> 4) * 8);
    qa[1] = ld_frag(q_lds, wave * 16 + (lane & 15), 32 + (lane >> 4) * 8);

    __syncthreads();

    f32x4 of[4] = {};
    float m_r[4], l_r[4];
#pragma unroll
    for (int r = 0; r < 4; r++) { m_r[r] = -1e30f; l_r[r] = 0.f; }

    const u16* pw = p_lds + wave * 1024;
    u16* pww      = p_lds + wave * 1024;

    for (int s0 = 0; s0 < LQ; s0 += 64) {
#pragma unroll
        for (int rr = 0; rr < 2; rr++) {
            int f = rr * 256 + tid;
            int row = f >> 3, c8 = f & 7;
            const u16* srck = kb + ((size_t)bh * LQ + s0 + row) * HD + ((c8 ^ (row & 7)) * 8);
            __builtin_amdgcn_global_load_lds(srck, k_lds + (size_t)(f & ~63) * 8, 16, 0, 0);
            const u16* srcv = vtb + ((size_t)bh * HD + row) * LQ + s0 + ((c8 ^ (row & 7)) * 8);
            __builtin_amdgcn_global_load_lds(srcv, v_lds + (size_t)(f & ~63) * 8, 16, 0, 0);
        }
        __syncthreads();

        // ---- S = Q @ K^T ----
        f32x4 sf[4] = {};
#pragma unroll
        for (int sub = 0; sub < 4; sub++) {
#pragma unroll
            for (int kk = 0; kk < 2; kk++) {
                bf16x8 kf = ld_frag(k_lds, sub * 16 + (lane & 15), kk * 32 + (lane >> 4) * 8);
                sf[sub] = MFMA16(qa[kk], kf, sf[sub]);
            }
        }

        int drel = s0 - q0;
        bool diag = (drel == -64) || (drel == 0) || (drel == 64);
        if (diag) {
#pragma unroll
            for (int sub = 0; sub < 4; sub++) {
#pragma unroll
                for (int r = 0; r < 4; r++) {
                    int tl = wave * 16 + (lane >> 4) * 4 + r;
                    int s  = s0 + sub * 16 + (lane & 15);
                    int i  = s - (q0 + tl) + 4;
                    if ((unsigned)i <= 8u) sf[sub][r] += R_lds[tl * 9 + i];
                }
            }
        }

        // ---- online softmax ----
        float tmax[4];
#pragma unroll
        for (int r = 0; r < 4; r++) {
            float m0 = fmaxf(fmaxf(sf[0][r], sf[1][r]), fmaxf(sf[2][r], sf[3][r]));
#pragma unroll
            for (int msk = 8; msk >= 1; msk >>= 1) m0 = fmaxf(m0, __shfl_xor(m0, msk, 64));
            tmax[r] = m0;
        }
#pragma unroll
        for (int r = 0; r < 4; r++) {
            float mn = fmaxf(m_r[r], tmax[r]);
            float sc = __expf(m_r[r] - mn);
            m_r[r] = mn;
            l_r[r] *= sc;
#pragma unroll
            for (int sub = 0; sub < 4; sub++) of[sub][r] *= sc;
        }
#pragma unroll
        for (int sub = 0; sub < 4; sub++) {
#pragma unroll
            for (int r = 0; r < 4; r++) {
                float p = __expf(sf[sub][r] - m_r[r]);
                l_r[r] += p;
                int q = (lane >> 4) * 4 + r;
                int off = (q * 128 + (sub * 16 + (lane & 15)) * 2) ^ ((q & 7) << 4);
                *(__bf16*)((char*)pww + off) = (__bf16)p;
            }
        }

        // ---- O += P @ V ----
#pragma unroll
        for (int kk = 0; kk < 2; kk++) {
            bf16x8 pa = ld_frag(pw, lane & 15, kk * 32 + (lane >> 4) * 8);
#pragma unroll
            for (int dsub = 0; dsub < 4; dsub++) {
                bf16x8 vf = ld_frag(v_lds, dsub * 16 + (lane & 15), kk * 32 + (lane >> 4) * 8);
                of[dsub] = MFMA16(pa, vf, of[dsub]);
            }
        }

        if (diag) {
#pragma unroll
            for (int r = 0; r < 4; r++) {
                int q  = (lane >> 4) * 4 + r;
                int tl = wave * 16 + q;
#pragma unroll
                for (int i = 0; i < 9; i++) {
                    int s  = q0 + tl + i - 4;
                    int sl = s - s0;
                    if ((unsigned)sl < 64u) {
                        int off = (q * 128 + sl * 2) ^ ((q & 7) << 4);
                        float p = (float)*(const __bf16*)((const char*)pww + off);
#pragma unroll
                        for (int dsub = 0; dsub < 4; dsub++)
                            of[dsub][r] += p * rv_lds[i * 64 + dsub * 16 + (lane & 15)];
                    }
                }
            }
        }
        __syncthreads();
    }

    // ---- final normalize + write hi|lo split rows (stride KPA) ----
#pragma unroll
    for (int r = 0; r < 4; r++) {
        float s = l_r[r];
#pragma unroll
        for (int msk = 8; msk >= 1; msk >>= 1) s += __shfl_xor(s, msk, 64);
        l_r[r] = 1.0f / s;
    }
    const int b = bh >> 4, h = bh & 15;
#pragma unroll
    for (int dsub = 0; dsub < 4; dsub++) {
#pragma unroll
        for (int r = 0; r < 4; r++) {
            int t = q0 + wave * 16 + (lane >> 4) * 4 + r;
            int e = h * 64 + dsub * 16 + (lane & 15);
            float v = of[dsub][r] * l_r[r];
            __bf16 hh, ll; split_bf16(v, hh, ll);
            __bf16* row = Ao + (size_t)(b * LQ + t) * KPA;
            row[e]        = hh;
            row[1024 + e] = ll;
        }
    }
}

// ---------------------------------------------------------------------------
extern "C" void kernel_launch(void* const* d_in, const int* in_sizes, int n_in,
                              void* d_out, int out_size, void* d_ws, size_t ws_size,
                              hipStream_t stream)
{
    const float* hidden = (const float*)d_in[0];
    const float* Wq = (const float*)d_in[1];
    const float* bq = (const float*)d_in[2];
    const float* Wk = (const float*)d_in[3];
    const float* bk = (const float*)d_in[4];
    const float* Wv = (const float*)d_in[5];
    const float* bv = (const float*)d_in[6];
    const float* Wo = (const float*)d_in[7];
    const float* bo = (const float*)d_in[8];
    const float* relk = (const float*)d_in[9];
    const float* relv = (const float*)d_in[10];

    char* w = (char*)d_ws;
    // Workspace layout: Ah/Ao 16 MB at 0; BTq at 16M, BTk at 22M, BTv at 28M
    // (contiguous N=3072 for the fused QKV GEMM); BTo at 34M; qbw 40M, kbw 48M,
    // vbw 56M, vtbw 64M; 72 MB total.
    __bf16* Ah   = (__bf16*)(w);
    __bf16* Ao   = (__bf16*)(w);
    __bf16* BTq  = (__bf16*)(w + (16u << 20));
    __bf16* BTk  = (__bf16*)(w + (22u << 20));
    __bf16* BTv  = (__bf16*)(w + (28u << 20));
    __bf16* BTo  = (__bf16*)(w + (34u << 20));
    __bf16* qbw  = (__bf16*)(w + (40u << 20));
    __bf16* kbw  = (__bf16*)(w + (48u << 20));
    __bf16* vbw  = (__bf16*)(w + (56u << 20));
    __bf16* vtbw = (__bf16*)(w + (64u << 20));
    float*  out  = (float*)d_out;

    conv_hidden<<<1024, 256, 0, stream>>>(hidden, Ah);
    conv_w<<<dim3(16, 16, 4), 256, 0, stream>>>(Wq, Wk, Wv, Wo, BTq, BTk, BTv, BTo);
    qkv_mfma<<<256, 512, 0, stream>>>((const u16*)Ah, (const u16*)BTq,
                                      bq, bk, bv, qbw, kbw, vbw);
    vtrans<<<dim3(16, 64), 256, 0, stream>>>(vbw, vtbw);
    attn_mfma<<<dim3(16, 64), 256, 0, stream>>>((const u16*)qbw, (const u16*)kbw,
        (const u16*)vtbw, relk, relv, Ao);
    oproj_mfma<<<256, 512, 0, stream>>>((const u16*)Ao, (const u16*)BTo, bo, out);
}